// Round 3
// baseline (151.341 us; speedup 1.0000x reference)
//
#include <hip/hip_runtime.h>

#define SEQ 2048
#define DIM 1280
#define NH 16
#define HD 80

typedef __attribute__((ext_vector_type(8))) short short8;
typedef __attribute__((ext_vector_type(4))) float f32x4;
typedef unsigned short u16;

__device__ inline u16 f2bf(float f) {
  unsigned u = __builtin_bit_cast(unsigned, f);
  u += 0x7FFFu + ((u >> 16) & 1u);
  return (u16)(u >> 16);
}
__device__ inline float bf2f(u16 h) {
  unsigned u = ((unsigned)h) << 16;
  return __builtin_bit_cast(float, u);
}

// async global->LDS, 16B per lane, dest = wave-uniform base + lane*16
#define GLOAD16(gsrc, ldst)                                                          \
  __builtin_amdgcn_global_load_lds((const __attribute__((address_space(1))) unsigned*)(gsrc), \
                                   (__attribute__((address_space(3))) unsigned*)(ldst), 16, 0, 0)

// ---------------- all f32 -> bf16 conversions in one launch ----------------
__global__ void cvt5(const float* __restrict__ s0, const float* __restrict__ s1,
                     const float* __restrict__ s2, const float* __restrict__ s3,
                     const float* __restrict__ s4, u16* __restrict__ hs_b,
                     u16* __restrict__ w_b, int nh, int nw) {
  int y = blockIdx.y;
  const float* src = y == 0 ? s0 : (y == 1 ? s1 : (y == 2 ? s2 : (y == 3 ? s3 : s4)));
  int n = y == 0 ? nh : nw;
  u16* dst = y == 0 ? hs_b : w_b + (long)(y - 1) * nw;
  int i = (blockIdx.x * 256 + threadIdx.x) * 4;
  if (i >= n) return;
  float4 v = *(const float4*)(src + i);
  ushort4 pk;
  pk.x = f2bf(v.x); pk.y = f2bf(v.y); pk.z = f2bf(v.z); pk.w = f2bf(v.w);
  *(ushort4*)(dst + i) = pk;
}

// ---------------- GEMM core: C[M,N] = A[M,K] * B[N,K]^T + bias ----------------
// m97 structure: 128x128 tile, BK=64, global_load_lds staging with
// source-side XOR swizzle (chunk c_lin holds data chunk c_lin^(row&7)),
// linear LDS dest, swizzled ds_read -> conflict-free b128 reads.
template <int OUTMODE>  // 0 = bf16 out, 1 = f32 out
__device__ void gemm_core(const u16* __restrict__ A, const u16* __restrict__ B,
                          const float* __restrict__ bias, void* __restrict__ Cout,
                          u16* __restrict__ vtg, int M, int N, int K) {
  __shared__ u16 As[128 * 64];
  __shared__ u16 Bs[128 * 64];
  const int tid = threadIdx.x;
  const int wave = tid >> 6;
  const int lane = tid & 63;
  const int wr = (wave >> 1) * 64, wc = (wave & 1) * 64;
  const int bm = blockIdx.x * 128, bn = blockIdx.y * 128;
  const int lrow = lane & 15, lgrp = lane >> 4;

  f32x4 acc[4][4] = {};

  // this thread's staging chunk geometry (cid = j*256 + tid)
  int srow[4], soff[4];
#pragma unroll
  for (int j = 0; j < 4; j++) {
    int cid = j * 256 + tid;
    srow[j] = cid >> 3;
    soff[j] = (((cid & 7) ^ (srow[j] & 7)) * 8);  // swizzled source chunk (shorts)
  }

  for (int k0 = 0; k0 < K; k0 += 64) {
    __syncthreads();
#pragma unroll
    for (int j = 0; j < 4; j++)
      GLOAD16(A + (long)(bm + srow[j]) * K + k0 + soff[j], &As[(j * 256 + wave * 64) * 8]);
#pragma unroll
    for (int j = 0; j < 4; j++)
      GLOAD16(B + (long)(bn + srow[j]) * K + k0 + soff[j], &Bs[(j * 256 + wave * 64) * 8]);
    __syncthreads();

#pragma unroll
    for (int ks = 0; ks < 2; ks++) {
      const int rc = ((ks * 4 + lgrp) ^ (lrow & 7)) * 8;  // swizzled read chunk
      short8 af[4], bfr[4];
#pragma unroll
      for (int i = 0; i < 4; i++)
        af[i] = *(const short8*)&As[(wr + i * 16 + lrow) * 64 + rc];
#pragma unroll
      for (int j = 0; j < 4; j++)
        bfr[j] = *(const short8*)&Bs[(wc + j * 16 + lrow) * 64 + rc];
#pragma unroll
      for (int i = 0; i < 4; i++)
#pragma unroll
        for (int j = 0; j < 4; j++)
          acc[i][j] = __builtin_amdgcn_mfma_f32_16x16x32_bf16(af[i], bfr[j], acc[i][j], 0, 0, 0);
    }
  }

  if (vtg) {
    // V output: write transposed [col][row] packed 4 rows per 8B store
#pragma unroll
    for (int i = 0; i < 4; i++) {
      int row0 = bm + wr + i * 16 + lgrp * 4;
#pragma unroll
      for (int j = 0; j < 4; j++) {
        int col = bn + wc + j * 16 + lrow;
        float bv = bias[col];
        ushort4 pk;
        pk.x = f2bf(acc[i][j][0] + bv);
        pk.y = f2bf(acc[i][j][1] + bv);
        pk.z = f2bf(acc[i][j][2] + bv);
        pk.w = f2bf(acc[i][j][3] + bv);
        *(ushort4*)(vtg + (long)col * SEQ + row0) = pk;
      }
    }
  } else {
#pragma unroll
    for (int i = 0; i < 4; i++) {
      int row = bm + wr + i * 16 + lgrp * 4;
#pragma unroll
      for (int j = 0; j < 4; j++) {
        int col = bn + wc + j * 16 + lrow;
        float bv = bias[col];
#pragma unroll
        for (int r = 0; r < 4; r++) {
          float v = acc[i][j][r] + bv;
          if (OUTMODE == 0)
            ((u16*)Cout)[(long)(row + r) * N + col] = f2bf(v);
          else
            ((float*)Cout)[(long)(row + r) * N + col] = v;
        }
      }
    }
  }
}

__global__ __launch_bounds__(256) void gemm_qkv(
    const u16* __restrict__ A, const u16* __restrict__ Bq,
    const u16* __restrict__ Bk, const u16* __restrict__ Bv,
    const float* __restrict__ bq, const float* __restrict__ bk,
    const float* __restrict__ bv, u16* __restrict__ Cq, u16* __restrict__ Ck,
    u16* __restrict__ vtg) {
  int z = blockIdx.z;
  if (z == 2) {
    gemm_core<0>(A, Bv, bv, nullptr, vtg, SEQ, DIM, DIM);
  } else {
    const u16* B = z == 0 ? Bq : Bk;
    const float* bias = z == 0 ? bq : bk;
    u16* C = z == 0 ? Cq : Ck;
    gemm_core<0>(A, B, bias, C, nullptr, SEQ, DIM, DIM);
  }
}

__global__ __launch_bounds__(256) void gemm_out(
    const u16* __restrict__ A, const u16* __restrict__ B,
    const float* __restrict__ bias, float* __restrict__ C) {
  gemm_core<1>(A, B, bias, C, nullptr, SEQ, DIM, DIM);
}

// ---------------- RoPE (in place on bf16 Q,K) ----------------
__global__ void rope_kernel(u16* __restrict__ Q, u16* __restrict__ Kt,
                            const float* __restrict__ cosT,
                            const float* __restrict__ sinT) {
  int idx = blockIdx.x * 256 + threadIdx.x;
  if (idx >= SEQ * NH * 40) return;
  int j = idx % 40;
  int t = idx / 40;
  int h = t & 15;
  int s = t >> 4;
  long base = (long)s * DIM + h * HD;
  float c0 = cosT[s * HD + j], s0 = sinT[s * HD + j];
  float c1 = cosT[s * HD + j + 40], s1 = sinT[s * HD + j + 40];
  float q0 = bf2f(Q[base + j]), q1 = bf2f(Q[base + j + 40]);
  Q[base + j] = f2bf(q0 * c0 - q1 * s0);
  Q[base + j + 40] = f2bf(q1 * c1 + q0 * s1);
  float k0 = bf2f(Kt[base + j]), k1 = bf2f(Kt[base + j + 40]);
  Kt[base + j] = f2bf(k0 * c0 - k1 * s0);
  Kt[base + j + 40] = f2bf(k1 * c1 + k0 * s1);
}

// ---------------- Flash attention v3: no cross-wave LDS, V^T from global ----
// block = (head, segment, 64-row q tile); 4 independent waves (16 q-rows each).
// S^T = mfma(K,Q): lane holds 32 keys for q-row = lane&15 -> local softmax.
// K and V^T fragments read straight from global (L2-resident).
__global__ __launch_bounds__(256) void attn_kernel(
    const u16* __restrict__ Q, const u16* __restrict__ K,
    const u16* __restrict__ VT, u16* __restrict__ O, const int* __restrict__ cu) {
  const int h = blockIdx.x;
  const int g = blockIdx.y;
  const int qt = blockIdx.z;
  const int s0 = cu[g], s1 = cu[g + 1];
  const int qbase = s0 + qt * 64;
  if (qbase >= s1) return;

  __shared__ u16 ps[4 * 16 * 128];  // per-wave P, XOR-swizzled; no barriers needed

  const int tid = threadIdx.x;
  const int wave = tid >> 6, lane = tid & 63;
  const int lrow = lane & 15, lgrp = lane >> 4;

  // Q fragments direct from global (B-operand: row = q = lrow)
  int qrow = qbase + wave * 16 + lrow;
  if (qrow > SEQ - 1) qrow = SEQ - 1;
  const u16* qptr = Q + (long)qrow * DIM + h * HD;
  short8 aq[3];
#pragma unroll
  for (int ks = 0; ks < 3; ks++) {
    short8 z = {};
    if (ks < 2 || lgrp < 2) z = *(const short8*)(qptr + ks * 32 + lgrp * 8);
    aq[ks] = z;
  }

  f32x4 o_acc[5] = {};
  float m_r = -1e30f, l_r = 0.f;
  const float scale = 0.11180339887498949f;  // 1/sqrt(80)

  const int nk = (s1 - s0 + 127) / 128;
  for (int ck = 0; ck < nk; ck++) {
    const int kb = s0 + ck * 128;

    // S^T = K * Q^T : sa[n] covers keys n*16..n*16+15 (row = key, col = q)
    f32x4 sa[8];
#pragma unroll
    for (int n = 0; n < 8; n++) sa[n] = (f32x4){0.f, 0.f, 0.f, 0.f};
#pragma unroll
    for (int n = 0; n < 8; n++) {
      int krow = kb + n * 16 + lrow;
      if (krow > SEQ - 1) krow = SEQ - 1;
      const u16* kp = K + (long)krow * DIM + h * HD;
#pragma unroll
      for (int ks = 0; ks < 3; ks++) {
        short8 kf = {};
        if (ks < 2 || lgrp < 2) kf = *(const short8*)(kp + ks * 32 + lgrp * 8);
        sa[n] = __builtin_amdgcn_mfma_f32_16x16x32_bf16(kf, aq[ks], sa[n], 0, 0, 0);
      }
    }

    // local softmax: lane holds keys n*16 + lgrp*4 + r for q-row lrow
    float pm = -1e30f;
    float pv[8][4];
#pragma unroll
    for (int n = 0; n < 8; n++)
#pragma unroll
      for (int r = 0; r < 4; r++) {
        int key = kb + n * 16 + lgrp * 4 + r;
        float v = (key < s1) ? sa[n][r] * scale : -1e30f;
        pv[n][r] = v;
        pm = fmaxf(pm, v);
      }
    pm = fmaxf(pm, __shfl_xor(pm, 16));
    pm = fmaxf(pm, __shfl_xor(pm, 32));
    float mnew = fmaxf(m_r, pm);
    float sc = __expf(m_r - mnew);
    float ls = 0.f;
#pragma unroll
    for (int n = 0; n < 8; n++)
#pragma unroll
      for (int r = 0; r < 4; r++) {
        float e = __expf(pv[n][r] - mnew);
        pv[n][r] = e;
        ls += e;
      }
    ls += __shfl_xor(ls, 16);
    ls += __shfl_xor(ls, 32);
    l_r = l_r * sc + ls;
    m_r = mnew;

    // rescale o_acc: factor for q-row lgrp*4+r lives at lane lrow==that row
#pragma unroll
    for (int r = 0; r < 4; r++) {
      float scr = __shfl(sc, lgrp * 4 + r);
#pragma unroll
      for (int nf = 0; nf < 5; nf++) o_acc[nf][r] *= scr;
    }

    // P -> per-wave LDS (packed 4 bf16 = 8B per n-group), swizzled
#pragma unroll
    for (int n = 0; n < 8; n++) {
      unsigned lo = (unsigned)f2bf(pv[n][0]) | ((unsigned)f2bf(pv[n][1]) << 16);
      unsigned hi = (unsigned)f2bf(pv[n][2]) | ((unsigned)f2bf(pv[n][3]) << 16);
      int keybase = n * 16 + lgrp * 4;
      int phys = (keybase >> 3) ^ lrow;
      unsigned* dst = (unsigned*)&ps[wave * 2048 + lrow * 128 + phys * 8 + (keybase & 7)];
      dst[0] = lo;
      dst[1] = hi;
    }

    // PV: o += P * V   (A = P rows=q, B-operand = V^T rows=d from global)
#pragma unroll
    for (int ks = 0; ks < 4; ks++) {
      int g8 = ks * 4 + lgrp;
      int sb = kb + g8 * 8;
      if (sb > SEQ - 8) sb = SEQ - 8;
      short8 pf = *(const short8*)&ps[wave * 2048 + lrow * 128 + (g8 ^ lrow) * 8];
#pragma unroll
      for (int nf = 0; nf < 5; nf++) {
        short8 vf = *(const short8*)(VT + (long)(h * HD + nf * 16 + lrow) * SEQ + sb);
        o_acc[nf] = __builtin_amdgcn_mfma_f32_16x16x32_bf16(pf, vf, o_acc[nf], 0, 0, 0);
      }
    }
  }

  // epilogue: normalize and write
#pragma unroll
  for (int r = 0; r < 4; r++) {
    float lr = __shfl(l_r, lgrp * 4 + r);
    float inv = 1.0f / lr;
    int row = qbase + wave * 16 + lgrp * 4 + r;
    if (row < s1) {
#pragma unroll
      for (int nf = 0; nf < 5; nf++)
        O[(long)row * DIM + h * HD + nf * 16 + lrow] = f2bf(o_acc[nf][r] * inv);
    }
  }
}

extern "C" void kernel_launch(void* const* d_in, const int* in_sizes, int n_in,
                              void* d_out, int out_size, void* d_ws, size_t ws_size,
                              hipStream_t stream) {
  const float* hs = (const float*)d_in[0];
  const float* Wq = (const float*)d_in[1];
  const float* bq = (const float*)d_in[2];
  const float* Wk = (const float*)d_in[3];
  const float* bk = (const float*)d_in[4];
  const float* Wv = (const float*)d_in[5];
  const float* bv = (const float*)d_in[6];
  const float* Wo = (const float*)d_in[7];
  const float* bo = (const float*)d_in[8];
  const float* cosT = (const float*)d_in[9];
  const float* sinT = (const float*)d_in[10];
  const int* cu = (const int*)d_in[11];
  const int nseg = in_sizes[11] - 1;  // 4

  char* ws = (char*)d_ws;
  u16* hs_b = (u16*)(ws);
  u16* wq_b = (u16*)(ws + 5242880);
  u16* wk_b = (u16*)(ws + 8519680);
  u16* wv_b = (u16*)(ws + 11796480);
  u16* wo_b = (u16*)(ws + 15073280);
  u16* q_b  = (u16*)(ws + 18350080);
  u16* k_b  = (u16*)(ws + 23592960);
  u16* vt_g = (u16*)(ws + 28835840);  // V^T [DIM][SEQ]
  u16* ao_b = (u16*)(ws + 34078720);

  const int nh = SEQ * DIM;   // 2621440
  const int nw = DIM * DIM;   // 1638400
  cvt5<<<dim3(nh / 1024, 5), 256, 0, stream>>>(hs, Wq, Wk, Wv, Wo, hs_b, wq_b, nh, nw);

  dim3 gq(SEQ / 128, DIM / 128, 3);
  gemm_qkv<<<gq, 256, 0, stream>>>(hs_b, wq_b, wk_b, wv_b, bq, bk, bv, q_b, k_b, vt_g);

  rope_kernel<<<(SEQ * NH * 40) / 256, 256, 0, stream>>>(q_b, k_b, cosT, sinT);

  dim3 ga(NH, nseg, (SEQ / nseg + 63) / 64);
  attn_kernel<<<ga, 256, 0, stream>>>(q_b, k_b, vt_g, ao_b, cu);

  dim3 go(SEQ / 128, DIM / 128, 1);
  gemm_out<<<go, 256, 0, stream>>>(ao_b, wo_b, bo, (float*)d_out);
}

// Round 4
// 123.820 us; speedup vs baseline: 1.2223x; 1.2223x over previous
//
#include <hip/hip_runtime.h>

#define SEQ 2048
#define DIM 1280
#define NH 16
#define HD 80

typedef __attribute__((ext_vector_type(8))) short short8;
typedef __attribute__((ext_vector_type(4))) float f32x4;
typedef unsigned short u16;

__device__ inline u16 f2bf(float f) {
  unsigned u = __builtin_bit_cast(unsigned, f);
  u += 0x7FFFu + ((u >> 16) & 1u);
  return (u16)(u >> 16);
}
__device__ inline float bf2f(u16 h) {
  unsigned u = ((unsigned)h) << 16;
  return __builtin_bit_cast(float, u);
}

// async global->LDS, 16B per lane, dest = wave-uniform base + lane*16
#define GLOAD16(gsrc, ldst)                                                          \
  __builtin_amdgcn_global_load_lds((const __attribute__((address_space(1))) unsigned*)(gsrc), \
                                   (__attribute__((address_space(3))) unsigned*)(ldst), 16, 0, 0)

// ---------------- all f32 -> bf16 conversions in one launch ----------------
__global__ void cvt5(const float* __restrict__ s0, const float* __restrict__ s1,
                     const float* __restrict__ s2, const float* __restrict__ s3,
                     const float* __restrict__ s4, u16* __restrict__ hs_b,
                     u16* __restrict__ w_b, int nh, int nw) {
  int y = blockIdx.y;
  const float* src = y == 0 ? s0 : (y == 1 ? s1 : (y == 2 ? s2 : (y == 3 ? s3 : s4)));
  int n = y == 0 ? nh : nw;
  u16* dst = y == 0 ? hs_b : w_b + (long)(y - 1) * nw;
  int i = (blockIdx.x * 256 + threadIdx.x) * 4;
  if (i >= n) return;
  float4 v = *(const float4*)(src + i);
  ushort4 pk;
  pk.x = f2bf(v.x); pk.y = f2bf(v.y); pk.z = f2bf(v.z); pk.w = f2bf(v.w);
  *(ushort4*)(dst + i) = pk;
}

// ---------------- GEMM: C[M,N] = A[M,K] * B[N,K]^T + bias ------------------
// BM=64 x BN=128 tile, BK=64, 4 waves (2x2, wave tile 32x64), double-buffered
// global_load_lds staging (issue-early 2-phase), source-side XOR swizzle with
// linear LDS dest + swizzled ds_read (conflict-free, verified R3).
// EPI=0: merged QKV epilogue (bf16 Q,K row-major; V transposed) over N=3840.
// EPI=1: f32 out + bias.
template <int EPI>
__global__ __launch_bounds__(256, 4) void gemm64(
    const u16* __restrict__ A, const u16* __restrict__ B, int N, int K,
    const float* __restrict__ b0, const float* __restrict__ b1,
    const float* __restrict__ b2, u16* __restrict__ outQ, u16* __restrict__ outK,
    u16* __restrict__ outVT, float* __restrict__ outF) {
  __shared__ u16 As[2][64 * 64];
  __shared__ u16 Bs[2][128 * 64];
  const int tid = threadIdx.x;
  const int wave = tid >> 6, lane = tid & 63;
  const int lrow = lane & 15, lgrp = lane >> 4;
  const int wr = (wave >> 1) * 32, wc = (wave & 1) * 64;

  // XCD-aware block swizzle (nwg % 8 == 0 for all our grids)
  const int nwg = gridDim.x;
  const int lid = blockIdx.x;
  const int wg = (lid & 7) * (nwg >> 3) + (lid >> 3);
  const int bnC = N >> 7;
  const int bm = wg / bnC, bn = wg % bnC;

  // per-thread staging geometry: chunk cid -> (row, swizzled 16B chunk)
  int rowA[2], offA[2], rowB[4], offB[4];
#pragma unroll
  for (int j = 0; j < 2; j++) {
    int cid = j * 256 + tid;
    rowA[j] = cid >> 3;
    offA[j] = ((cid & 7) ^ (rowA[j] & 7)) * 8;
  }
#pragma unroll
  for (int j = 0; j < 4; j++) {
    int cid = j * 256 + tid;
    rowB[j] = cid >> 3;
    offB[j] = ((cid & 7) ^ (rowB[j] & 7)) * 8;
  }
  const u16* Abase = A + (long)bm * 64 * K;
  const u16* Bbase = B + (long)bn * 128 * K;

  f32x4 acc[2][4] = {};
  const int NT = K >> 6;

  // prologue: stage tile 0 into buf 0
#pragma unroll
  for (int j = 0; j < 2; j++)
    GLOAD16(Abase + (long)rowA[j] * K + offA[j], &As[0][(j * 256 + wave * 64) * 8]);
#pragma unroll
  for (int j = 0; j < 4; j++)
    GLOAD16(Bbase + (long)rowB[j] * K + offB[j], &Bs[0][(j * 256 + wave * 64) * 8]);
  __syncthreads();

  for (int t = 0; t < NT; t++) {
    const int cur = t & 1;
    if (t + 1 < NT) {  // issue next-tile loads BEFORE compute (T3 2-phase)
      const int k0 = (t + 1) << 6;
      const int nxt = cur ^ 1;
#pragma unroll
      for (int j = 0; j < 2; j++)
        GLOAD16(Abase + (long)rowA[j] * K + k0 + offA[j], &As[nxt][(j * 256 + wave * 64) * 8]);
#pragma unroll
      for (int j = 0; j < 4; j++)
        GLOAD16(Bbase + (long)rowB[j] * K + k0 + offB[j], &Bs[nxt][(j * 256 + wave * 64) * 8]);
    }
#pragma unroll
    for (int ks = 0; ks < 2; ks++) {
      const int rc = ((ks * 4 + lgrp) ^ (lrow & 7)) * 8;
      short8 af[2], bfr[4];
#pragma unroll
      for (int i = 0; i < 2; i++)
        af[i] = *(const short8*)&As[cur][(wr + i * 16 + lrow) * 64 + rc];
#pragma unroll
      for (int j = 0; j < 4; j++)
        bfr[j] = *(const short8*)&Bs[cur][(wc + j * 16 + lrow) * 64 + rc];
#pragma unroll
      for (int i = 0; i < 2; i++)
#pragma unroll
        for (int j = 0; j < 4; j++)
          acc[i][j] = __builtin_amdgcn_mfma_f32_16x16x32_bf16(af[i], bfr[j], acc[i][j], 0, 0, 0);
    }
    __syncthreads();  // vmcnt(0)+barrier: next tile staged, cur free for reuse
  }

  // epilogue
#pragma unroll
  for (int i = 0; i < 2; i++) {
    int row0 = bm * 64 + wr + i * 16 + lgrp * 4;
#pragma unroll
    for (int j = 0; j < 4; j++) {
      int col = bn * 128 + wc + j * 16 + lrow;
      if (EPI == 0) {
        int which = col / 1280;  // uniform per block (128 | 1280)
        int cl = col - which * 1280;
        const float* bias = which == 0 ? b0 : (which == 1 ? b1 : b2);
        float bv = bias[cl];
        if (which == 2) {  // V: write transposed, 4 consecutive rows pack to 8B
          ushort4 pk;
          pk.x = f2bf(acc[i][j][0] + bv);
          pk.y = f2bf(acc[i][j][1] + bv);
          pk.z = f2bf(acc[i][j][2] + bv);
          pk.w = f2bf(acc[i][j][3] + bv);
          *(ushort4*)(outVT + (long)cl * SEQ + row0) = pk;
        } else {
          u16* o = which == 0 ? outQ : outK;
#pragma unroll
          for (int r = 0; r < 4; r++)
            o[(long)(row0 + r) * DIM + cl] = f2bf(acc[i][j][r] + bv);
        }
      } else {
        float bv = b0[col];
#pragma unroll
        for (int r = 0; r < 4; r++)
          outF[(long)(row0 + r) * DIM + col] = acc[i][j][r] + bv;
      }
    }
  }
}

// ---------------- RoPE (in place on bf16 Q,K) ----------------
__global__ void rope_kernel(u16* __restrict__ Q, u16* __restrict__ Kt,
                            const float* __restrict__ cosT,
                            const float* __restrict__ sinT) {
  int idx = blockIdx.x * 256 + threadIdx.x;
  if (idx >= SEQ * NH * 40) return;
  int j = idx % 40;
  int t = idx / 40;
  int h = t & 15;
  int s = t >> 4;
  long base = (long)s * DIM + h * HD;
  float c0 = cosT[s * HD + j], s0 = sinT[s * HD + j];
  float c1 = cosT[s * HD + j + 40], s1 = sinT[s * HD + j + 40];
  float q0 = bf2f(Q[base + j]), q1 = bf2f(Q[base + j + 40]);
  Q[base + j] = f2bf(q0 * c0 - q1 * s0);
  Q[base + j + 40] = f2bf(q1 * c1 + q0 * s1);
  float k0 = bf2f(Kt[base + j]), k1 = bf2f(Kt[base + j + 40]);
  Kt[base + j] = f2bf(k0 * c0 - k1 * s0);
  Kt[base + j + 40] = f2bf(k1 * c1 + k0 * s1);
}

// ---------------- Flash attention v3: no cross-wave LDS, V^T from global ----
__global__ __launch_bounds__(256) void attn_kernel(
    const u16* __restrict__ Q, const u16* __restrict__ K,
    const u16* __restrict__ VT, u16* __restrict__ O, const int* __restrict__ cu) {
  const int h = blockIdx.x;
  const int g = blockIdx.y;
  const int qt = blockIdx.z;
  const int s0 = cu[g], s1 = cu[g + 1];
  const int qbase = s0 + qt * 64;
  if (qbase >= s1) return;

  __shared__ u16 ps[4 * 16 * 128];  // per-wave P, XOR-swizzled; no barriers

  const int tid = threadIdx.x;
  const int wave = tid >> 6, lane = tid & 63;
  const int lrow = lane & 15, lgrp = lane >> 4;

  int qrow = qbase + wave * 16 + lrow;
  if (qrow > SEQ - 1) qrow = SEQ - 1;
  const u16* qptr = Q + (long)qrow * DIM + h * HD;
  short8 aq[3];
#pragma unroll
  for (int ks = 0; ks < 3; ks++) {
    short8 z = {};
    if (ks < 2 || lgrp < 2) z = *(const short8*)(qptr + ks * 32 + lgrp * 8);
    aq[ks] = z;
  }

  f32x4 o_acc[5] = {};
  float m_r = -1e30f, l_r = 0.f;
  const float scale = 0.11180339887498949f;  // 1/sqrt(80)

  const int nk = (s1 - s0 + 127) / 128;
  for (int ck = 0; ck < nk; ck++) {
    const int kb = s0 + ck * 128;

    f32x4 sa[8];
#pragma unroll
    for (int n = 0; n < 8; n++) sa[n] = (f32x4){0.f, 0.f, 0.f, 0.f};
#pragma unroll
    for (int n = 0; n < 8; n++) {
      int krow = kb + n * 16 + lrow;
      if (krow > SEQ - 1) krow = SEQ - 1;
      const u16* kp = K + (long)krow * DIM + h * HD;
#pragma unroll
      for (int ks = 0; ks < 3; ks++) {
        short8 kf = {};
        if (ks < 2 || lgrp < 2) kf = *(const short8*)(kp + ks * 32 + lgrp * 8);
        sa[n] = __builtin_amdgcn_mfma_f32_16x16x32_bf16(kf, aq[ks], sa[n], 0, 0, 0);
      }
    }

    float pm = -1e30f;
    float pv[8][4];
#pragma unroll
    for (int n = 0; n < 8; n++)
#pragma unroll
      for (int r = 0; r < 4; r++) {
        int key = kb + n * 16 + lgrp * 4 + r;
        float v = (key < s1) ? sa[n][r] * scale : -1e30f;
        pv[n][r] = v;
        pm = fmaxf(pm, v);
      }
    pm = fmaxf(pm, __shfl_xor(pm, 16));
    pm = fmaxf(pm, __shfl_xor(pm, 32));
    float mnew = fmaxf(m_r, pm);
    float sc = __expf(m_r - mnew);
    float ls = 0.f;
#pragma unroll
    for (int n = 0; n < 8; n++)
#pragma unroll
      for (int r = 0; r < 4; r++) {
        float e = __expf(pv[n][r] - mnew);
        pv[n][r] = e;
        ls += e;
      }
    ls += __shfl_xor(ls, 16);
    ls += __shfl_xor(ls, 32);
    l_r = l_r * sc + ls;
    m_r = mnew;

#pragma unroll
    for (int r = 0; r < 4; r++) {
      float scr = __shfl(sc, lgrp * 4 + r);
#pragma unroll
      for (int nf = 0; nf < 5; nf++) o_acc[nf][r] *= scr;
    }

#pragma unroll
    for (int n = 0; n < 8; n++) {
      unsigned lo = (unsigned)f2bf(pv[n][0]) | ((unsigned)f2bf(pv[n][1]) << 16);
      unsigned hi = (unsigned)f2bf(pv[n][2]) | ((unsigned)f2bf(pv[n][3]) << 16);
      int keybase = n * 16 + lgrp * 4;
      int phys = (keybase >> 3) ^ lrow;
      unsigned* dst = (unsigned*)&ps[wave * 2048 + lrow * 128 + phys * 8 + (keybase & 7)];
      dst[0] = lo;
      dst[1] = hi;
    }

#pragma unroll
    for (int ks = 0; ks < 4; ks++) {
      int g8 = ks * 4 + lgrp;
      int sb = kb + g8 * 8;
      if (sb > SEQ - 8) sb = SEQ - 8;
      short8 pf = *(const short8*)&ps[wave * 2048 + lrow * 128 + (g8 ^ lrow) * 8];
#pragma unroll
      for (int nf = 0; nf < 5; nf++) {
        short8 vf = *(const short8*)(VT + (long)(h * HD + nf * 16 + lrow) * SEQ + sb);
        o_acc[nf] = __builtin_amdgcn_mfma_f32_16x16x32_bf16(pf, vf, o_acc[nf], 0, 0, 0);
      }
    }
  }

#pragma unroll
  for (int r = 0; r < 4; r++) {
    float lr = __shfl(l_r, lgrp * 4 + r);
    float inv = 1.0f / lr;
    int row = qbase + wave * 16 + lgrp * 4 + r;
    if (row < s1) {
#pragma unroll
      for (int nf = 0; nf < 5; nf++)
        O[(long)row * DIM + h * HD + nf * 16 + lrow] = f2bf(o_acc[nf][r] * inv);
    }
  }
}

extern "C" void kernel_launch(void* const* d_in, const int* in_sizes, int n_in,
                              void* d_out, int out_size, void* d_ws, size_t ws_size,
                              hipStream_t stream) {
  const float* hs = (const float*)d_in[0];
  const float* Wq = (const float*)d_in[1];
  const float* bq = (const float*)d_in[2];
  const float* Wk = (const float*)d_in[3];
  const float* bk = (const float*)d_in[4];
  const float* Wv = (const float*)d_in[5];
  const float* bv = (const float*)d_in[6];
  const float* Wo = (const float*)d_in[7];
  const float* bo = (const float*)d_in[8];
  const float* cosT = (const float*)d_in[9];
  const float* sinT = (const float*)d_in[10];
  const int* cu = (const int*)d_in[11];
  const int nseg = in_sizes[11] - 1;  // 4

  char* ws = (char*)d_ws;
  u16* hs_b = (u16*)(ws);
  u16* wq_b = (u16*)(ws + 5242880);   // [Wq;Wk;Wv;Wo] contiguous bf16
  u16* wo_b = (u16*)(ws + 15073280);
  u16* q_b  = (u16*)(ws + 18350080);
  u16* k_b  = (u16*)(ws + 23592960);
  u16* vt_g = (u16*)(ws + 28835840);  // V^T [DIM][SEQ]
  u16* ao_b = (u16*)(ws + 34078720);

  const int nh = SEQ * DIM;   // 2621440
  const int nw = DIM * DIM;   // 1638400
  cvt5<<<dim3(nh / 1024, 5), 256, 0, stream>>>(hs, Wq, Wk, Wv, Wo, hs_b, wq_b, nh, nw);

  // merged QKV GEMM: N = 3840, grid = 32*30 = 960 blocks
  gemm64<0><<<(SEQ / 64) * (3 * DIM / 128), 256, 0, stream>>>(
      hs_b, wq_b, 3 * DIM, DIM, bq, bk, bv, q_b, k_b, vt_g, nullptr);

  rope_kernel<<<(SEQ * NH * 40) / 256, 256, 0, stream>>>(q_b, k_b, cosT, sinT);

  dim3 ga(NH, nseg, (SEQ / nseg + 63) / 64);
  attn_kernel<<<ga, 256, 0, stream>>>(q_b, k_b, vt_g, ao_b, cu);

  // O-proj: grid = 32*10 = 320 blocks
  gemm64<1><<<(SEQ / 64) * (DIM / 128), 256, 0, stream>>>(
      ao_b, wo_b, DIM, DIM, bo, nullptr, nullptr, nullptr, nullptr, nullptr,
      (float*)d_out);
}

// Round 5
// 92.223 us; speedup vs baseline: 1.6410x; 1.3426x over previous
//
#include <hip/hip_runtime.h>

#define SEQ 2048
#define DIM 1280
#define NH 16
#define HD 80

typedef __attribute__((ext_vector_type(8))) short short8;
typedef __attribute__((ext_vector_type(4))) float f32x4;
typedef unsigned short u16;

__device__ inline u16 f2bf(float f) {
  unsigned u = __builtin_bit_cast(unsigned, f);
  u += 0x7FFFu + ((u >> 16) & 1u);
  return (u16)(u >> 16);
}
__device__ inline float bf2f(u16 h) {
  unsigned u = ((unsigned)h) << 16;
  return __builtin_bit_cast(float, u);
}

// async global->LDS, 16B per lane, dest = wave-uniform base + lane*16
#define GLOAD16(gsrc, ldst)                                                          \
  __builtin_amdgcn_global_load_lds((const __attribute__((address_space(1))) unsigned*)(gsrc), \
                                   (__attribute__((address_space(3))) unsigned*)(ldst), 16, 0, 0)

// ---------------- all f32 -> bf16 conversions in one launch ----------------
__global__ void cvt5(const float* __restrict__ s0, const float* __restrict__ s1,
                     const float* __restrict__ s2, const float* __restrict__ s3,
                     const float* __restrict__ s4, u16* __restrict__ hs_b,
                     u16* __restrict__ w_b, int nh, int nw) {
  int y = blockIdx.y;
  const float* src = y == 0 ? s0 : (y == 1 ? s1 : (y == 2 ? s2 : (y == 3 ? s3 : s4)));
  int n = y == 0 ? nh : nw;
  u16* dst = y == 0 ? hs_b : w_b + (long)(y - 1) * nw;
  int i = (blockIdx.x * 256 + threadIdx.x) * 4;
  if (i >= n) return;
  float4 v = *(const float4*)(src + i);
  ushort4 pk;
  pk.x = f2bf(v.x); pk.y = f2bf(v.y); pk.z = f2bf(v.z); pk.w = f2bf(v.w);
  *(ushort4*)(dst + i) = pk;
}

// ------------- QKV GEMM: 128x128 tile, BK=64, 4 waves (64x64 each, 4x4) -----
// issue-early double-buffered global_load_lds staging, src-XOR-swizzle +
// swizzled ds_read (conflict-free). Outputs: Q,K head-major [h][s][80],
// V transposed [1280][SEQ].
__global__ __launch_bounds__(256) void gemm_qkv128(
    const u16* __restrict__ A, const u16* __restrict__ B,
    const float* __restrict__ b0, const float* __restrict__ b1,
    const float* __restrict__ b2, u16* __restrict__ outQ, u16* __restrict__ outK,
    u16* __restrict__ outVT) {
  __shared__ u16 As[2][128 * 64];
  __shared__ u16 Bs[2][128 * 64];
  const int N = 3 * DIM, K = DIM;
  const int tid = threadIdx.x;
  const int wave = tid >> 6, lane = tid & 63;
  const int lrow = lane & 15, lgrp = lane >> 4;
  const int wr = (wave >> 1) * 64, wc = (wave & 1) * 64;

  // XCD swizzle, bn-major ordering (B-panel L2-hot per XCD chunk)
  const int nwg = gridDim.x;  // 480, %8==0
  const int lid = blockIdx.x;
  const int wg = (lid & 7) * (nwg >> 3) + (lid >> 3);
  const int bm = wg & 15, bn = wg >> 4;  // M blocks = 16, N blocks = 30

  int rowS[4], offS[4];
#pragma unroll
  for (int j = 0; j < 4; j++) {
    int cid = j * 256 + tid;
    rowS[j] = cid >> 3;
    offS[j] = ((cid & 7) ^ (rowS[j] & 7)) * 8;
  }
  const u16* Abase = A + (long)bm * 128 * K;
  const u16* Bbase = B + (long)bn * 128 * K;

  f32x4 acc[4][4] = {};
  const int NT = K >> 6;  // 20

#pragma unroll
  for (int j = 0; j < 4; j++)
    GLOAD16(Abase + (long)rowS[j] * K + offS[j], &As[0][(j * 256 + wave * 64) * 8]);
#pragma unroll
  for (int j = 0; j < 4; j++)
    GLOAD16(Bbase + (long)rowS[j] * K + offS[j], &Bs[0][(j * 256 + wave * 64) * 8]);
  __syncthreads();

  for (int t = 0; t < NT; t++) {
    const int cur = t & 1;
    if (t + 1 < NT) {
      const int k0 = (t + 1) << 6;
      const int nxt = cur ^ 1;
#pragma unroll
      for (int j = 0; j < 4; j++)
        GLOAD16(Abase + (long)rowS[j] * K + k0 + offS[j], &As[nxt][(j * 256 + wave * 64) * 8]);
#pragma unroll
      for (int j = 0; j < 4; j++)
        GLOAD16(Bbase + (long)rowS[j] * K + k0 + offS[j], &Bs[nxt][(j * 256 + wave * 64) * 8]);
    }
#pragma unroll
    for (int ks = 0; ks < 2; ks++) {
      const int rc = ((ks * 4 + lgrp) ^ (lrow & 7)) * 8;
      short8 af[4], bfr[4];
#pragma unroll
      for (int i = 0; i < 4; i++)
        af[i] = *(const short8*)&As[cur][(wr + i * 16 + lrow) * 64 + rc];
#pragma unroll
      for (int j = 0; j < 4; j++)
        bfr[j] = *(const short8*)&Bs[cur][(wc + j * 16 + lrow) * 64 + rc];
#pragma unroll
      for (int i = 0; i < 4; i++)
#pragma unroll
        for (int j = 0; j < 4; j++)
          acc[i][j] = __builtin_amdgcn_mfma_f32_16x16x32_bf16(af[i], bfr[j], acc[i][j], 0, 0, 0);
    }
    __syncthreads();
  }

#pragma unroll
  for (int i = 0; i < 4; i++) {
    int row0 = bm * 128 + wr + i * 16 + lgrp * 4;
#pragma unroll
    for (int j = 0; j < 4; j++) {
      int col = bn * 128 + wc + j * 16 + lrow;
      int which = col / 1280;          // uniform per fragment
      int cl = col - which * 1280;
      const float* bias = which == 0 ? b0 : (which == 1 ? b1 : b2);
      float bv = bias[cl];
      if (which == 2) {  // V^T: 4 consecutive seq rows pack into one 8B store
        ushort4 pk;
        pk.x = f2bf(acc[i][j][0] + bv);
        pk.y = f2bf(acc[i][j][1] + bv);
        pk.z = f2bf(acc[i][j][2] + bv);
        pk.w = f2bf(acc[i][j][3] + bv);
        *(ushort4*)(outVT + (long)cl * SEQ + row0) = pk;
      } else {  // Q/K head-major [h][s][80]
        int hh = cl / 80, d = cl - hh * 80;
        u16* o = (which == 0 ? outQ : outK) + ((long)hh * SEQ + row0) * 80 + d;
#pragma unroll
        for (int r = 0; r < 4; r++) o[r * 80] = f2bf(acc[i][j][r] + bv);
      }
    }
  }
}

// ------------- O-proj GEMM (R4 structure: BM=64, BN=128, 2x4 frags) --------
__global__ __launch_bounds__(256) void gemm_oproj(
    const u16* __restrict__ A, const u16* __restrict__ B,
    const float* __restrict__ b0, float* __restrict__ outF) {
  __shared__ u16 As[2][64 * 64];
  __shared__ u16 Bs[2][128 * 64];
  const int N = DIM, K = DIM;
  const int tid = threadIdx.x;
  const int wave = tid >> 6, lane = tid & 63;
  const int lrow = lane & 15, lgrp = lane >> 4;
  const int wr = (wave >> 1) * 32, wc = (wave & 1) * 64;

  const int nwg = gridDim.x;  // 320
  const int lid = blockIdx.x;
  const int wg = (lid & 7) * (nwg >> 3) + (lid >> 3);
  const int bnC = N >> 7;
  const int bm = wg / bnC, bn = wg % bnC;

  int rowA[2], offA[2], rowB[4], offB[4];
#pragma unroll
  for (int j = 0; j < 2; j++) {
    int cid = j * 256 + tid;
    rowA[j] = cid >> 3;
    offA[j] = ((cid & 7) ^ (rowA[j] & 7)) * 8;
  }
#pragma unroll
  for (int j = 0; j < 4; j++) {
    int cid = j * 256 + tid;
    rowB[j] = cid >> 3;
    offB[j] = ((cid & 7) ^ (rowB[j] & 7)) * 8;
  }
  const u16* Abase = A + (long)bm * 64 * K;
  const u16* Bbase = B + (long)bn * 128 * K;

  f32x4 acc[2][4] = {};
  const int NT = K >> 6;

#pragma unroll
  for (int j = 0; j < 2; j++)
    GLOAD16(Abase + (long)rowA[j] * K + offA[j], &As[0][(j * 256 + wave * 64) * 8]);
#pragma unroll
  for (int j = 0; j < 4; j++)
    GLOAD16(Bbase + (long)rowB[j] * K + offB[j], &Bs[0][(j * 256 + wave * 64) * 8]);
  __syncthreads();

  for (int t = 0; t < NT; t++) {
    const int cur = t & 1;
    if (t + 1 < NT) {
      const int k0 = (t + 1) << 6;
      const int nxt = cur ^ 1;
#pragma unroll
      for (int j = 0; j < 2; j++)
        GLOAD16(Abase + (long)rowA[j] * K + k0 + offA[j], &As[nxt][(j * 256 + wave * 64) * 8]);
#pragma unroll
      for (int j = 0; j < 4; j++)
        GLOAD16(Bbase + (long)rowB[j] * K + k0 + offB[j], &Bs[nxt][(j * 256 + wave * 64) * 8]);
    }
#pragma unroll
    for (int ks = 0; ks < 2; ks++) {
      const int rc = ((ks * 4 + lgrp) ^ (lrow & 7)) * 8;
      short8 af[2], bfr[4];
#pragma unroll
      for (int i = 0; i < 2; i++)
        af[i] = *(const short8*)&As[cur][(wr + i * 16 + lrow) * 64 + rc];
#pragma unroll
      for (int j = 0; j < 4; j++)
        bfr[j] = *(const short8*)&Bs[cur][(wc + j * 16 + lrow) * 64 + rc];
#pragma unroll
      for (int i = 0; i < 2; i++)
#pragma unroll
        for (int j = 0; j < 4; j++)
          acc[i][j] = __builtin_amdgcn_mfma_f32_16x16x32_bf16(af[i], bfr[j], acc[i][j], 0, 0, 0);
    }
    __syncthreads();
  }

#pragma unroll
  for (int i = 0; i < 2; i++) {
    int row0 = bm * 64 + wr + i * 16 + lgrp * 4;
#pragma unroll
    for (int j = 0; j < 4; j++) {
      int col = bn * 128 + wc + j * 16 + lrow;
      float bv = b0[col];
#pragma unroll
      for (int r = 0; r < 4; r++)
        outF[(long)(row0 + r) * DIM + col] = acc[i][j][r] + bv;
    }
  }
}

// ---------------- RoPE (in place, head-major Q,K) ----------------
__global__ void rope_kernel(u16* __restrict__ Q, u16* __restrict__ Kt,
                            const float* __restrict__ cosT,
                            const float* __restrict__ sinT) {
  int idx = blockIdx.x * 256 + threadIdx.x;
  if (idx >= NH * SEQ * 40) return;
  int j = idx % 40;
  int t = idx / 40;
  int s = t & (SEQ - 1);
  int h = t >> 11;
  long base = ((long)h * SEQ + s) * 80;
  float c0 = cosT[s * HD + j], s0 = sinT[s * HD + j];
  float c1 = cosT[s * HD + j + 40], s1 = sinT[s * HD + j + 40];
  float q0 = bf2f(Q[base + j]), q1 = bf2f(Q[base + j + 40]);
  Q[base + j] = f2bf(q0 * c0 - q1 * s0);
  Q[base + j + 40] = f2bf(q1 * c1 + q0 * s1);
  float k0 = bf2f(Kt[base + j]), k1 = bf2f(Kt[base + j + 40]);
  Kt[base + j] = f2bf(k0 * c0 - k1 * s0);
  Kt[base + j + 40] = f2bf(k1 * c1 + k0 * s1);
}

// ---------------- Flash attention v4: LDS-staged K/V^T, dbuf, KVBLK=64 -----
// Q,K head-major [h][s][80]; VT [1280][SEQ] (per-head [80][SEQ]).
// Swapped QK^T (mfma(K,Q)) -> lane-local softmax over 16 keys.
__global__ __launch_bounds__(256) void attn_kernel(
    const u16* __restrict__ Q, const u16* __restrict__ K,
    const u16* __restrict__ VT, u16* __restrict__ O, const int* __restrict__ cu) {
  const int h = blockIdx.x;
  const int g = blockIdx.y;
  const int qt = blockIdx.z;
  const int s0 = cu[g], s1 = cu[g + 1];
  const int qbase = s0 + qt * 64;
  if (qbase >= s1) return;

  __shared__ u16 k_s[2][64 * 80];   // [key][d], 16B chunks XOR-swizzled (c<8)
  __shared__ u16 vt_s[2][80 * 64];  // [d][key], 8 chunks/row XOR-swizzled
  __shared__ u16 ps[4 * 16 * 64];   // per-wave P [qrow][key], swizzled

  const int tid = threadIdx.x;
  const int wave = tid >> 6, lane = tid & 63;
  const int lrow = lane & 15, lgrp = lane >> 4;

  const u16* Kh = K + (long)h * SEQ * 80;
  const u16* Vh = VT + (long)h * 80 * SEQ;

  // Q fragments from global (one-time gather), head-major
  int qrow = qbase + wave * 16 + lrow;
  const u16* qptr = Q + ((long)h * SEQ + qrow) * 80;
  short8 aq[3];
#pragma unroll
  for (int ks = 0; ks < 3; ks++) {
    short8 z = {};
    if (ks < 2 || lgrp < 2) z = *(const short8*)(qptr + ks * 32 + lgrp * 8);
    aq[ks] = z;
  }

  f32x4 o_acc[5] = {};
  float m_r = -1e30f, l_r = 0.f;
  const float scale = 0.11180339887498949f;  // 1/sqrt(80)

  const int nk = (s1 - s0 + 63) / 64;  // 8

  // staging: K tile 640 chunks, VT tile 640 chunks
#define STAGE_KV(buf, kb)                                                          \
  {                                                                                \
    _Pragma("unroll") for (int j = 0; j < 2; j++) {                                \
      int chunk = j * 256 + tid;                                                   \
      int krow = chunk / 10, c = chunk - krow * 10;                                \
      int cs = c < 8 ? (c ^ (krow & 7)) : c;                                       \
      GLOAD16(Kh + ((long)((kb) + krow)) * 80 + cs * 8,                            \
              &k_s[buf][(j * 256 + wave * 64) * 8]);                               \
    }                                                                              \
    if (tid < 128) {                                                               \
      int chunk = 512 + tid;                                                       \
      int krow = chunk / 10, c = chunk - krow * 10;                                \
      int cs = c < 8 ? (c ^ (krow & 7)) : c;                                       \
      GLOAD16(Kh + ((long)((kb) + krow)) * 80 + cs * 8,                            \
              &k_s[buf][(512 + wave * 64) * 8]);                                   \
    }                                                                              \
    _Pragma("unroll") for (int j = 0; j < 2; j++) {                                \
      int chunk = j * 256 + tid;                                                   \
      int d = chunk >> 3, c = chunk & 7;                                           \
      GLOAD16(Vh + (long)d * SEQ + (kb) + ((c ^ (d & 7)) * 8),                     \
              &vt_s[buf][(j * 256 + wave * 64) * 8]);                              \
    }                                                                              \
    if (tid < 128) {                                                               \
      int chunk = 512 + tid;                                                       \
      int d = chunk >> 3, c = chunk & 7;                                           \
      GLOAD16(Vh + (long)d * SEQ + (kb) + ((c ^ (d & 7)) * 8),                     \
              &vt_s[buf][(512 + wave * 64) * 8]);                                  \
    }                                                                              \
  }

  STAGE_KV(0, s0);
  __syncthreads();

  for (int ck = 0; ck < nk; ck++) {
    const int kb = s0 + ck * 64;
    const int cur = ck & 1;
    if (ck + 1 < nk) STAGE_KV(cur ^ 1, kb + 64);

    // S^T = K * Q^T : sa[n] = keys n*16..+15 (rows), q cols
    f32x4 sa[4] = {};
#pragma unroll
    for (int n = 0; n < 4; n++) {
      int row = n * 16 + lrow;
#pragma unroll
      for (int ks = 0; ks < 3; ks++) {
        short8 kf = {};
        if (ks < 2) {
          int cl = (ks * 4 + lgrp) ^ (row & 7);
          kf = *(const short8*)&k_s[cur][row * 80 + cl * 8];
        } else if (lgrp < 2) {
          kf = *(const short8*)&k_s[cur][row * 80 + (8 + lgrp) * 8];
        }
        sa[n] = __builtin_amdgcn_mfma_f32_16x16x32_bf16(kf, aq[ks], sa[n], 0, 0, 0);
      }
    }

    // lane-local softmax (16 keys per lane for q-row lrow)
    float pm = -1e30f;
    float pv[4][4];
#pragma unroll
    for (int n = 0; n < 4; n++)
#pragma unroll
      for (int r = 0; r < 4; r++) {
        float v = sa[n][r] * scale;
        pv[n][r] = v;
        pm = fmaxf(pm, v);
      }
    pm = fmaxf(pm, __shfl_xor(pm, 16));
    pm = fmaxf(pm, __shfl_xor(pm, 32));
    float mnew = fmaxf(m_r, pm);
    float sc = __expf(m_r - mnew);
    float ls = 0.f;
#pragma unroll
    for (int n = 0; n < 4; n++)
#pragma unroll
      for (int r = 0; r < 4; r++) {
        float e = __expf(pv[n][r] - mnew);
        pv[n][r] = e;
        ls += e;
      }
    ls += __shfl_xor(ls, 16);
    ls += __shfl_xor(ls, 32);
    l_r = l_r * sc + ls;
    m_r = mnew;

#pragma unroll
    for (int r = 0; r < 4; r++) {
      float scr = __shfl(sc, lgrp * 4 + r);
#pragma unroll
      for (int nf = 0; nf < 5; nf++) o_acc[nf][r] *= scr;
    }

    // P -> per-wave LDS (8B packed), swizzled
#pragma unroll
    for (int n = 0; n < 4; n++) {
      uint2 w;
      w.x = (unsigned)f2bf(pv[n][0]) | ((unsigned)f2bf(pv[n][1]) << 16);
      w.y = (unsigned)f2bf(pv[n][2]) | ((unsigned)f2bf(pv[n][3]) << 16);
      int keybase = n * 16 + lgrp * 4;
      int cw = (keybase >> 3) ^ (lrow & 7);
      *(uint2*)&ps[wave * 1024 + lrow * 64 + cw * 8 + (keybase & 7)] = w;
    }

    // PV: o += P * V (A = P rows=q, B = V^T rows=d)
#pragma unroll
    for (int ks = 0; ks < 2; ks++) {
      int g8 = ks * 4 + lgrp;
      short8 pf = *(const short8*)&ps[wave * 1024 + lrow * 64 + (g8 ^ (lrow & 7)) * 8];
#pragma unroll
      for (int nf = 0; nf < 5; nf++) {
        int row = nf * 16 + lrow;
        short8 vf = *(const short8*)&vt_s[cur][row * 64 + (g8 ^ (row & 7)) * 8];
        o_acc[nf] = __builtin_amdgcn_mfma_f32_16x16x32_bf16(pf, vf, o_acc[nf], 0, 0, 0);
      }
    }
    __syncthreads();
  }

  // epilogue: normalize, write row-major [s][1280] for O-proj
#pragma unroll
  for (int r = 0; r < 4; r++) {
    float lr = __shfl(l_r, lgrp * 4 + r);
    float inv = 1.0f / lr;
    int row = qbase + wave * 16 + lgrp * 4 + r;
#pragma unroll
    for (int nf = 0; nf < 5; nf++)
      O[(long)row * DIM + h * HD + nf * 16 + lrow] = f2bf(o_acc[nf][r] * inv);
  }
}

extern "C" void kernel_launch(void* const* d_in, const int* in_sizes, int n_in,
                              void* d_out, int out_size, void* d_ws, size_t ws_size,
                              hipStream_t stream) {
  const float* hs = (const float*)d_in[0];
  const float* Wq = (const float*)d_in[1];
  const float* bq = (const float*)d_in[2];
  const float* Wk = (const float*)d_in[3];
  const float* bk = (const float*)d_in[4];
  const float* Wv = (const float*)d_in[5];
  const float* bv = (const float*)d_in[6];
  const float* Wo = (const float*)d_in[7];
  const float* bo = (const float*)d_in[8];
  const float* cosT = (const float*)d_in[9];
  const float* sinT = (const float*)d_in[10];
  const int* cu = (const int*)d_in[11];
  const int nseg = in_sizes[11] - 1;  // 4

  char* ws = (char*)d_ws;
  u16* hs_b = (u16*)(ws);
  u16* wq_b = (u16*)(ws + 5242880);   // [Wq;Wk;Wv;Wo] contiguous bf16
  u16* wo_b = (u16*)(ws + 15073280);
  u16* q_b  = (u16*)(ws + 18350080);  // head-major [16][2048][80]
  u16* k_b  = (u16*)(ws + 23592960);  // head-major
  u16* vt_g = (u16*)(ws + 28835840);  // V^T [1280][2048]
  u16* ao_b = (u16*)(ws + 34078720);  // [2048][1280]

  const int nh = SEQ * DIM;
  const int nw = DIM * DIM;
  cvt5<<<dim3(nh / 1024, 5), 256, 0, stream>>>(hs, Wq, Wk, Wv, Wo, hs_b, wq_b, nh, nw);

  // merged QKV GEMM: grid = 16*30 = 480 blocks
  gemm_qkv128<<<(SEQ / 128) * (3 * DIM / 128), 256, 0, stream>>>(
      hs_b, wq_b, bq, bk, bv, q_b, k_b, vt_g);

  rope_kernel<<<(NH * SEQ * 40) / 256, 256, 0, stream>>>(q_b, k_b, cosT, sinT);

  dim3 ga(NH, nseg, (SEQ / nseg + 63) / 64);
  attn_kernel<<<ga, 256, 0, stream>>>(q_b, k_b, vt_g, ao_b, cu);

  // O-proj: grid = 32*10 = 320 blocks
  gemm_oproj<<<(SEQ / 64) * (DIM / 128), 256, 0, stream>>>(ao_b, wo_b, bo,
                                                           (float*)d_out);
}

// Round 6
// 88.086 us; speedup vs baseline: 1.7181x; 1.0470x over previous
//
#include <hip/hip_runtime.h>

#define SEQ 2048
#define DIM 1280
#define NH 16
#define HD 80

typedef __attribute__((ext_vector_type(8))) short short8;
typedef __attribute__((ext_vector_type(4))) float f32x4;
typedef unsigned short u16;

__device__ inline u16 f2bf(float f) {
  unsigned u = __builtin_bit_cast(unsigned, f);
  u += 0x7FFFu + ((u >> 16) & 1u);
  return (u16)(u >> 16);
}
__device__ inline float bf2f(u16 h) {
  unsigned u = ((unsigned)h) << 16;
  return __builtin_bit_cast(float, u);
}

// async global->LDS, 16B per lane, dest = wave-uniform base + lane*16
#define GLOAD16(gsrc, ldst)                                                          \
  __builtin_amdgcn_global_load_lds((const __attribute__((address_space(1))) unsigned*)(gsrc), \
                                   (__attribute__((address_space(3))) unsigned*)(ldst), 16, 0, 0)

// ---------------- all f32 -> bf16 conversions in one launch ----------------
__global__ void cvt5(const float* __restrict__ s0, const float* __restrict__ s1,
                     const float* __restrict__ s2, const float* __restrict__ s3,
                     const float* __restrict__ s4, u16* __restrict__ hs_b,
                     u16* __restrict__ w_b, int nh, int nw) {
  int y = blockIdx.y;
  const float* src = y == 0 ? s0 : (y == 1 ? s1 : (y == 2 ? s2 : (y == 3 ? s3 : s4)));
  int n = y == 0 ? nh : nw;
  u16* dst = y == 0 ? hs_b : w_b + (long)(y - 1) * nw;
  int i = (blockIdx.x * 256 + threadIdx.x) * 4;
  if (i >= n) return;
  float4 v = *(const float4*)(src + i);
  ushort4 pk;
  pk.x = f2bf(v.x); pk.y = f2bf(v.y); pk.z = f2bf(v.z); pk.w = f2bf(v.w);
  *(ushort4*)(dst + i) = pk;
}

// ------------- QKV GEMM: 128x128 tile, BK=64, 8 waves (64x32 each, 4x2) -----
// 512 threads for 2x the waves/CU (grid is the occupancy cap at 480 blocks).
// issue-early double-buffered global_load_lds staging, src-XOR-swizzle +
// swizzled ds_read (conflict-free). Outputs: Q,K head-major [h][s][80],
// V transposed [1280][SEQ].
__global__ __launch_bounds__(512) void gemm_qkv128(
    const u16* __restrict__ A, const u16* __restrict__ B,
    const float* __restrict__ b0, const float* __restrict__ b1,
    const float* __restrict__ b2, u16* __restrict__ outQ, u16* __restrict__ outK,
    u16* __restrict__ outVT) {
  __shared__ u16 As[2][128 * 64];
  __shared__ u16 Bs[2][128 * 64];
  const int K = DIM;
  const int tid = threadIdx.x;
  const int wave = tid >> 6, lane = tid & 63;
  const int lrow = lane & 15, lgrp = lane >> 4;
  const int wr = (wave >> 2) * 64, wc = (wave & 3) * 32;

  // XCD swizzle, bm-fastest (consecutive wg share B-panel)
  const int nwg = gridDim.x;  // 480, %8==0
  const int lid = blockIdx.x;
  const int wg = (lid & 7) * (nwg >> 3) + (lid >> 3);
  const int bm = wg & 15, bn = wg >> 4;  // 16 M-blocks, 30 N-blocks

  // staging chunks: cid = j*512 + tid, 1024 chunks per tile
  int rowS[2], offS[2];
#pragma unroll
  for (int j = 0; j < 2; j++) {
    int cid = j * 512 + tid;
    rowS[j] = cid >> 3;
    offS[j] = ((cid & 7) ^ (rowS[j] & 7)) * 8;
  }
  const u16* Abase = A + (long)bm * 128 * K;
  const u16* Bbase = B + (long)bn * 128 * K;

  f32x4 acc[4][2] = {};
  const int NT = K >> 6;  // 20

#pragma unroll
  for (int j = 0; j < 2; j++)
    GLOAD16(Abase + (long)rowS[j] * K + offS[j], &As[0][(j * 512 + wave * 64) * 8]);
#pragma unroll
  for (int j = 0; j < 2; j++)
    GLOAD16(Bbase + (long)rowS[j] * K + offS[j], &Bs[0][(j * 512 + wave * 64) * 8]);
  __syncthreads();

  for (int t = 0; t < NT; t++) {
    const int cur = t & 1;
    if (t + 1 < NT) {  // issue next-tile loads BEFORE compute
      const int k0 = (t + 1) << 6;
      const int nxt = cur ^ 1;
#pragma unroll
      for (int j = 0; j < 2; j++)
        GLOAD16(Abase + (long)rowS[j] * K + k0 + offS[j], &As[nxt][(j * 512 + wave * 64) * 8]);
#pragma unroll
      for (int j = 0; j < 2; j++)
        GLOAD16(Bbase + (long)rowS[j] * K + k0 + offS[j], &Bs[nxt][(j * 512 + wave * 64) * 8]);
    }
#pragma unroll
    for (int ks = 0; ks < 2; ks++) {
      const int rc = ((ks * 4 + lgrp) ^ (lrow & 7)) * 8;
      short8 af[4], bfr[2];
#pragma unroll
      for (int i = 0; i < 4; i++)
        af[i] = *(const short8*)&As[cur][(wr + i * 16 + lrow) * 64 + rc];
#pragma unroll
      for (int j = 0; j < 2; j++)
        bfr[j] = *(const short8*)&Bs[cur][(wc + j * 16 + lrow) * 64 + rc];
#pragma unroll
      for (int i = 0; i < 4; i++)
#pragma unroll
        for (int j = 0; j < 2; j++)
          acc[i][j] = __builtin_amdgcn_mfma_f32_16x16x32_bf16(af[i], bfr[j], acc[i][j], 0, 0, 0);
    }
    __syncthreads();
  }

#pragma unroll
  for (int i = 0; i < 4; i++) {
    int row0 = bm * 128 + wr + i * 16 + lgrp * 4;
#pragma unroll
    for (int j = 0; j < 2; j++) {
      int col = bn * 128 + wc + j * 16 + lrow;
      int which = col / 1280;  // uniform per block (bn-decided)
      int cl = col - which * 1280;
      const float* bias = which == 0 ? b0 : (which == 1 ? b1 : b2);
      float bv = bias[cl];
      if (which == 2) {  // V^T: 4 consecutive seq rows pack into one 8B store
        ushort4 pk;
        pk.x = f2bf(acc[i][j][0] + bv);
        pk.y = f2bf(acc[i][j][1] + bv);
        pk.z = f2bf(acc[i][j][2] + bv);
        pk.w = f2bf(acc[i][j][3] + bv);
        *(ushort4*)(outVT + (long)cl * SEQ + row0) = pk;
      } else {  // Q/K head-major [h][s][80]
        int hh = cl / 80, d = cl - hh * 80;
        u16* o = (which == 0 ? outQ : outK) + ((long)hh * SEQ + row0) * 80 + d;
#pragma unroll
        for (int r = 0; r < 4; r++) o[r * 80] = f2bf(acc[i][j][r] + bv);
      }
    }
  }
}

// ------------- O-proj GEMM: 64x128 tile, BK=64, 8 waves (32x32 each) -------
__global__ __launch_bounds__(512) void gemm_oproj(
    const u16* __restrict__ A, const u16* __restrict__ B,
    const float* __restrict__ b0, float* __restrict__ outF) {
  __shared__ u16 As[2][64 * 64];
  __shared__ u16 Bs[2][128 * 64];
  const int N = DIM, K = DIM;
  const int tid = threadIdx.x;
  const int wave = tid >> 6, lane = tid & 63;
  const int lrow = lane & 15, lgrp = lane >> 4;
  const int wr = (wave >> 2) * 32, wc = (wave & 3) * 32;

  const int nwg = gridDim.x;  // 320
  const int lid = blockIdx.x;
  const int wg = (lid & 7) * (nwg >> 3) + (lid >> 3);
  const int bnC = N >> 7;
  const int bm = wg / bnC, bn = wg % bnC;

  // A: 512 chunks (1 per thread); B: 1024 chunks (2 per thread)
  const int rowA = tid >> 3;
  const int offA = ((tid & 7) ^ (rowA & 7)) * 8;
  int rowB[2], offB[2];
#pragma unroll
  for (int j = 0; j < 2; j++) {
    int cid = j * 512 + tid;
    rowB[j] = cid >> 3;
    offB[j] = ((cid & 7) ^ (rowB[j] & 7)) * 8;
  }
  const u16* Abase = A + (long)bm * 64 * K;
  const u16* Bbase = B + (long)bn * 128 * K;

  f32x4 acc[2][2] = {};
  const int NT = K >> 6;

  GLOAD16(Abase + (long)rowA * K + offA, &As[0][(wave * 64) * 8]);
#pragma unroll
  for (int j = 0; j < 2; j++)
    GLOAD16(Bbase + (long)rowB[j] * K + offB[j], &Bs[0][(j * 512 + wave * 64) * 8]);
  __syncthreads();

  for (int t = 0; t < NT; t++) {
    const int cur = t & 1;
    if (t + 1 < NT) {
      const int k0 = (t + 1) << 6;
      const int nxt = cur ^ 1;
      GLOAD16(Abase + (long)rowA * K + k0 + offA, &As[nxt][(wave * 64) * 8]);
#pragma unroll
      for (int j = 0; j < 2; j++)
        GLOAD16(Bbase + (long)rowB[j] * K + k0 + offB[j], &Bs[nxt][(j * 512 + wave * 64) * 8]);
    }
#pragma unroll
    for (int ks = 0; ks < 2; ks++) {
      const int rc = ((ks * 4 + lgrp) ^ (lrow & 7)) * 8;
      short8 af[2], bfr[2];
#pragma unroll
      for (int i = 0; i < 2; i++)
        af[i] = *(const short8*)&As[cur][(wr + i * 16 + lrow) * 64 + rc];
#pragma unroll
      for (int j = 0; j < 2; j++)
        bfr[j] = *(const short8*)&Bs[cur][(wc + j * 16 + lrow) * 64 + rc];
#pragma unroll
      for (int i = 0; i < 2; i++)
#pragma unroll
        for (int j = 0; j < 2; j++)
          acc[i][j] = __builtin_amdgcn_mfma_f32_16x16x32_bf16(af[i], bfr[j], acc[i][j], 0, 0, 0);
    }
    __syncthreads();
  }

#pragma unroll
  for (int i = 0; i < 2; i++) {
    int row0 = bm * 64 + wr + i * 16 + lgrp * 4;
#pragma unroll
    for (int j = 0; j < 2; j++) {
      int col = bn * 128 + wc + j * 16 + lrow;
      float bv = b0[col];
#pragma unroll
      for (int r = 0; r < 4; r++)
        outF[(long)(row0 + r) * DIM + col] = acc[i][j][r] + bv;
    }
  }
}

// ---------------- RoPE (in place, head-major Q,K) ----------------
__global__ void rope_kernel(u16* __restrict__ Q, u16* __restrict__ Kt,
                            const float* __restrict__ cosT,
                            const float* __restrict__ sinT) {
  int idx = blockIdx.x * 256 + threadIdx.x;
  if (idx >= NH * SEQ * 40) return;
  int j = idx % 40;
  int t = idx / 40;
  int s = t & (SEQ - 1);
  int h = t >> 11;
  long base = ((long)h * SEQ + s) * 80;
  float c0 = cosT[s * HD + j], s0 = sinT[s * HD + j];
  float c1 = cosT[s * HD + j + 40], s1 = sinT[s * HD + j + 40];
  float q0 = bf2f(Q[base + j]), q1 = bf2f(Q[base + j + 40]);
  Q[base + j] = f2bf(q0 * c0 - q1 * s0);
  Q[base + j + 40] = f2bf(q1 * c1 + q0 * s1);
  float k0 = bf2f(Kt[base + j]), k1 = bf2f(Kt[base + j + 40]);
  Kt[base + j] = f2bf(k0 * c0 - k1 * s0);
  Kt[base + j + 40] = f2bf(k1 * c1 + k0 * s1);
}

// ---------------- Flash attention v4: LDS-staged K/V^T, dbuf, KVBLK=64 -----
// Q,K head-major [h][s][80]; VT [1280][SEQ] (per-head [80][SEQ]).
// Swapped QK^T (mfma(K,Q)) -> lane-local softmax over 16 keys.
__global__ __launch_bounds__(256) void attn_kernel(
    const u16* __restrict__ Q, const u16* __restrict__ K,
    const u16* __restrict__ VT, u16* __restrict__ O, const int* __restrict__ cu) {
  const int h = blockIdx.x;
  const int g = blockIdx.y;
  const int qt = blockIdx.z;
  const int s0 = cu[g], s1 = cu[g + 1];
  const int qbase = s0 + qt * 64;
  if (qbase >= s1) return;

  __shared__ u16 k_s[2][64 * 80];   // [key][d], 16B chunks XOR-swizzled (c<8)
  __shared__ u16 vt_s[2][80 * 64];  // [d][key], 8 chunks/row XOR-swizzled
  __shared__ u16 ps[4 * 16 * 64];   // per-wave P [qrow][key], swizzled

  const int tid = threadIdx.x;
  const int wave = tid >> 6, lane = tid & 63;
  const int lrow = lane & 15, lgrp = lane >> 4;

  const u16* Kh = K + (long)h * SEQ * 80;
  const u16* Vh = VT + (long)h * 80 * SEQ;

  // Q fragments from global (one-time gather), head-major
  int qrow = qbase + wave * 16 + lrow;
  const u16* qptr = Q + ((long)h * SEQ + qrow) * 80;
  short8 aq[3];
#pragma unroll
  for (int ks = 0; ks < 3; ks++) {
    short8 z = {};
    if (ks < 2 || lgrp < 2) z = *(const short8*)(qptr + ks * 32 + lgrp * 8);
    aq[ks] = z;
  }

  f32x4 o_acc[5] = {};
  float m_r = -1e30f, l_r = 0.f;
  const float scale = 0.11180339887498949f;  // 1/sqrt(80)

  const int nk = (s1 - s0 + 63) / 64;  // 8

#define STAGE_KV(buf, kb)                                                          \
  {                                                                                \
    _Pragma("unroll") for (int j = 0; j < 2; j++) {                                \
      int chunk = j * 256 + tid;                                                   \
      int krow = chunk / 10, c = chunk - krow * 10;                                \
      int cs = c < 8 ? (c ^ (krow & 7)) : c;                                       \
      GLOAD16(Kh + ((long)((kb) + krow)) * 80 + cs * 8,                            \
              &k_s[buf][(j * 256 + wave * 64) * 8]);                               \
    }                                                                              \
    if (tid < 128) {                                                               \
      int chunk = 512 + tid;                                                       \
      int krow = chunk / 10, c = chunk - krow * 10;                                \
      int cs = c < 8 ? (c ^ (krow & 7)) : c;                                       \
      GLOAD16(Kh + ((long)((kb) + krow)) * 80 + cs * 8,                            \
              &k_s[buf][(512 + wave * 64) * 8]);                                   \
    }                                                                              \
    _Pragma("unroll") for (int j = 0; j < 2; j++) {                                \
      int chunk = j * 256 + tid;                                                   \
      int d = chunk >> 3, c = chunk & 7;                                           \
      GLOAD16(Vh + (long)d * SEQ + (kb) + ((c ^ (d & 7)) * 8),                     \
              &vt_s[buf][(j * 256 + wave * 64) * 8]);                              \
    }                                                                              \
    if (tid < 128) {                                                               \
      int chunk = 512 + tid;                                                       \
      int d = chunk >> 3, c = chunk & 7;                                           \
      GLOAD16(Vh + (long)d * SEQ + (kb) + ((c ^ (d & 7)) * 8),                     \
              &vt_s[buf][(512 + wave * 64) * 8]);                                  \
    }                                                                              \
  }

  STAGE_KV(0, s0);
  __syncthreads();

  for (int ck = 0; ck < nk; ck++) {
    const int kb = s0 + ck * 64;
    const int cur = ck & 1;
    if (ck + 1 < nk) STAGE_KV(cur ^ 1, kb + 64);

    // S^T = K * Q^T : sa[n] = keys n*16..+15 (rows), q cols
    f32x4 sa[4] = {};
#pragma unroll
    for (int n = 0; n < 4; n++) {
      int row = n * 16 + lrow;
#pragma unroll
      for (int ks = 0; ks < 3; ks++) {
        short8 kf = {};
        if (ks < 2) {
          int cl = (ks * 4 + lgrp) ^ (row & 7);
          kf = *(const short8*)&k_s[cur][row * 80 + cl * 8];
        } else if (lgrp < 2) {
          kf = *(const short8*)&k_s[cur][row * 80 + (8 + lgrp) * 8];
        }
        sa[n] = __builtin_amdgcn_mfma_f32_16x16x32_bf16(kf, aq[ks], sa[n], 0, 0, 0);
      }
    }

    // lane-local softmax (16 keys per lane for q-row lrow)
    float pm = -1e30f;
    float pv[4][4];
#pragma unroll
    for (int n = 0; n < 4; n++)
#pragma unroll
      for (int r = 0; r < 4; r++) {
        float v = sa[n][r] * scale;
        pv[n][r] = v;
        pm = fmaxf(pm, v);
      }
    pm = fmaxf(pm, __shfl_xor(pm, 16));
    pm = fmaxf(pm, __shfl_xor(pm, 32));
    float mnew = fmaxf(m_r, pm);
    float sc = __expf(m_r - mnew);
    float ls = 0.f;
#pragma unroll
    for (int n = 0; n < 4; n++)
#pragma unroll
      for (int r = 0; r < 4; r++) {
        float e = __expf(pv[n][r] - mnew);
        pv[n][r] = e;
        ls += e;
      }
    ls += __shfl_xor(ls, 16);
    ls += __shfl_xor(ls, 32);
    l_r = l_r * sc + ls;
    m_r = mnew;

#pragma unroll
    for (int r = 0; r < 4; r++) {
      float scr = __shfl(sc, lgrp * 4 + r);
#pragma unroll
      for (int nf = 0; nf < 5; nf++) o_acc[nf][r] *= scr;
    }

    // P -> per-wave LDS (8B packed), swizzled
#pragma unroll
    for (int n = 0; n < 4; n++) {
      uint2 w;
      w.x = (unsigned)f2bf(pv[n][0]) | ((unsigned)f2bf(pv[n][1]) << 16);
      w.y = (unsigned)f2bf(pv[n][2]) | ((unsigned)f2bf(pv[n][3]) << 16);
      int keybase = n * 16 + lgrp * 4;
      int cw = (keybase >> 3) ^ (lrow & 7);
      *(uint2*)&ps[wave * 1024 + lrow * 64 + cw * 8 + (keybase & 7)] = w;
    }

    // PV: o += P * V (A = P rows=q, B = V^T rows=d)
#pragma unroll
    for (int ks = 0; ks < 2; ks++) {
      int g8 = ks * 4 + lgrp;
      short8 pf = *(const short8*)&ps[wave * 1024 + lrow * 64 + (g8 ^ (lrow & 7)) * 8];
#pragma unroll
      for (int nf = 0; nf < 5; nf++) {
        int row = nf * 16 + lrow;
        short8 vf = *(const short8*)&vt_s[cur][row * 64 + (g8 ^ (row & 7)) * 8];
        o_acc[nf] = __builtin_amdgcn_mfma_f32_16x16x32_bf16(pf, vf, o_acc[nf], 0, 0, 0);
      }
    }
    __syncthreads();
  }

  // epilogue: normalize, write row-major [s][1280] for O-proj
#pragma unroll
  for (int r = 0; r < 4; r++) {
    float lr = __shfl(l_r, lgrp * 4 + r);
    float inv = 1.0f / lr;
    int row = qbase + wave * 16 + lgrp * 4 + r;
#pragma unroll
    for (int nf = 0; nf < 5; nf++)
      O[(long)row * DIM + h * HD + nf * 16 + lrow] = f2bf(o_acc[nf][r] * inv);
  }
}

extern "C" void kernel_launch(void* const* d_in, const int* in_sizes, int n_in,
                              void* d_out, int out_size, void* d_ws, size_t ws_size,
                              hipStream_t stream) {
  const float* hs = (const float*)d_in[0];
  const float* Wq = (const float*)d_in[1];
  const float* bq = (const float*)d_in[2];
  const float* Wk = (const float*)d_in[3];
  const float* bk = (const float*)d_in[4];
  const float* Wv = (const float*)d_in[5];
  const float* bv = (const float*)d_in[6];
  const float* Wo = (const float*)d_in[7];
  const float* bo = (const float*)d_in[8];
  const float* cosT = (const float*)d_in[9];
  const float* sinT = (const float*)d_in[10];
  const int* cu = (const int*)d_in[11];
  const int nseg = in_sizes[11] - 1;  // 4

  char* ws = (char*)d_ws;
  u16* hs_b = (u16*)(ws);
  u16* wq_b = (u16*)(ws + 5242880);   // [Wq;Wk;Wv;Wo] contiguous bf16
  u16* wo_b = (u16*)(ws + 15073280);
  u16* q_b  = (u16*)(ws + 18350080);  // head-major [16][2048][80]
  u16* k_b  = (u16*)(ws + 23592960);  // head-major
  u16* vt_g = (u16*)(ws + 28835840);  // V^T [1280][2048]
  u16* ao_b = (u16*)(ws + 34078720);  // [2048][1280]

  const int nh = SEQ * DIM;
  const int nw = DIM * DIM;
  cvt5<<<dim3(nh / 1024, 5), 256, 0, stream>>>(hs, Wq, Wk, Wv, Wo, hs_b, wq_b, nh, nw);

  // merged QKV GEMM: grid = 16*30 = 480 blocks, 512 threads
  gemm_qkv128<<<(SEQ / 128) * (3 * DIM / 128), 512, 0, stream>>>(
      hs_b, wq_b, bq, bk, bv, q_b, k_b, vt_g);

  rope_kernel<<<(NH * SEQ * 40) / 256, 256, 0, stream>>>(q_b, k_b, cosT, sinT);

  dim3 ga(NH, nseg, (SEQ / nseg + 63) / 64);
  attn_kernel<<<ga, 256, 0, stream>>>(q_b, k_b, vt_g, ao_b, cu);

  // O-proj: grid = 32*10 = 320 blocks, 512 threads
  gemm_oproj<<<(SEQ / 64) * (DIM / 128), 512, 0, stream>>>(ao_b, wo_b, bo,
                                                           (float*)d_out);
}

// Round 7
// 84.235 us; speedup vs baseline: 1.7966x; 1.0457x over previous
//
#include <hip/hip_runtime.h>

#define SEQ 2048
#define DIM 1280
#define NH 16
#define HD 80

typedef __attribute__((ext_vector_type(8))) short short8;
typedef __attribute__((ext_vector_type(4))) float f32x4;
typedef unsigned short u16;

__device__ inline u16 f2bf(float f) {
  unsigned u = __builtin_bit_cast(unsigned, f);
  u += 0x7FFFu + ((u >> 16) & 1u);
  return (u16)(u >> 16);
}
__device__ inline float bf2f(u16 h) {
  unsigned u = ((unsigned)h) << 16;
  return __builtin_bit_cast(float, u);
}

// async global->LDS, 16B per lane, dest = wave-uniform base + lane*16
#define GLOAD16(gsrc, ldst)                                                          \
  __builtin_amdgcn_global_load_lds((const __attribute__((address_space(1))) unsigned*)(gsrc), \
                                   (__attribute__((address_space(3))) unsigned*)(ldst), 16, 0, 0)

#define ACQ_BARRIER()                    \
  __builtin_amdgcn_s_barrier();          \
  __builtin_amdgcn_sched_barrier(0)

// ---------------- all f32 -> bf16 conversions in one launch ----------------
__global__ void cvt5(const float* __restrict__ s0, const float* __restrict__ s1,
                     const float* __restrict__ s2, const float* __restrict__ s3,
                     const float* __restrict__ s4, u16* __restrict__ hs_b,
                     u16* __restrict__ w_b, int nh, int nw) {
  int y = blockIdx.y;
  const float* src = y == 0 ? s0 : (y == 1 ? s1 : (y == 2 ? s2 : (y == 3 ? s3 : s4)));
  int n = y == 0 ? nh : nw;
  u16* dst = y == 0 ? hs_b : w_b + (long)(y - 1) * nw;
  int i = (blockIdx.x * 256 + threadIdx.x) * 4;
  if (i >= n) return;
  float4 v = *(const float4*)(src + i);
  ushort4 pk;
  pk.x = f2bf(v.x); pk.y = f2bf(v.y); pk.z = f2bf(v.z); pk.w = f2bf(v.w);
  *(ushort4*)(dst + i) = pk;
}

// ------------- QKV GEMM: 128x128 tile, BK=64, 8 waves (64x32 each, 4x2) -----
// Counted-vmcnt double-buffer (T4): stage(t+1) -> s_waitcnt vmcnt(4) ->
// barrier -> compute(t) -> barrier. Loads never drained in main loop.
__global__ __launch_bounds__(512) void gemm_qkv128(
    const u16* __restrict__ A, const u16* __restrict__ B,
    const float* __restrict__ b0, const float* __restrict__ b1,
    const float* __restrict__ b2, u16* __restrict__ outQ, u16* __restrict__ outK,
    u16* __restrict__ outVT) {
  __shared__ u16 As[2][128 * 64];
  __shared__ u16 Bs[2][128 * 64];
  const int K = DIM;
  const int tid = threadIdx.x;
  const int wave = tid >> 6, lane = tid & 63;
  const int lrow = lane & 15, lgrp = lane >> 4;
  const int wr = (wave >> 2) * 64, wc = (wave & 3) * 32;

  const int nwg = gridDim.x;  // 480, %8==0
  const int lid = blockIdx.x;
  const int wg = (lid & 7) * (nwg >> 3) + (lid >> 3);
  const int bm = wg & 15, bn = wg >> 4;  // 16 M-blocks, 30 N-blocks

  int rowS[2], offS[2];
#pragma unroll
  for (int j = 0; j < 2; j++) {
    int cid = j * 512 + tid;
    rowS[j] = cid >> 3;
    offS[j] = ((cid & 7) ^ (rowS[j] & 7)) * 8;
  }
  const u16* Abase = A + (long)bm * 128 * K;
  const u16* Bbase = B + (long)bn * 128 * K;

  f32x4 acc[4][2] = {};
  const int NT = K >> 6;  // 20

#define QKV_STAGE(buf, k0)                                                         \
  {                                                                                \
    _Pragma("unroll") for (int j = 0; j < 2; j++)                                  \
        GLOAD16(Abase + (long)rowS[j] * K + (k0) + offS[j],                        \
                &As[buf][(j * 512 + wave * 64) * 8]);                              \
    _Pragma("unroll") for (int j = 0; j < 2; j++)                                  \
        GLOAD16(Bbase + (long)rowS[j] * K + (k0) + offS[j],                        \
                &Bs[buf][(j * 512 + wave * 64) * 8]);                              \
  }

  QKV_STAGE(0, 0);

  for (int t = 0; t < NT; t++) {
    const int cur = t & 1;
    if (t + 1 < NT) {
      QKV_STAGE(cur ^ 1, (t + 1) << 6);
      asm volatile("s_waitcnt vmcnt(4)" ::: "memory");
    } else {
      asm volatile("s_waitcnt vmcnt(0)" ::: "memory");
    }
    ACQ_BARRIER();
#pragma unroll
    for (int ks = 0; ks < 2; ks++) {
      const int rc = ((ks * 4 + lgrp) ^ (lrow & 7)) * 8;
      short8 af[4], bfr[2];
#pragma unroll
      for (int i = 0; i < 4; i++)
        af[i] = *(const short8*)&As[cur][(wr + i * 16 + lrow) * 64 + rc];
#pragma unroll
      for (int j = 0; j < 2; j++)
        bfr[j] = *(const short8*)&Bs[cur][(wc + j * 16 + lrow) * 64 + rc];
#pragma unroll
      for (int i = 0; i < 4; i++)
#pragma unroll
        for (int j = 0; j < 2; j++)
          acc[i][j] = __builtin_amdgcn_mfma_f32_16x16x32_bf16(af[i], bfr[j], acc[i][j], 0, 0, 0);
    }
    __builtin_amdgcn_s_barrier();  // release: all reads of cur done
  }

#pragma unroll
  for (int i = 0; i < 4; i++) {
    int row0 = bm * 128 + wr + i * 16 + lgrp * 4;
#pragma unroll
    for (int j = 0; j < 2; j++) {
      int col = bn * 128 + wc + j * 16 + lrow;
      int which = col / 1280;  // uniform per block (bn-decided)
      int cl = col - which * 1280;
      const float* bias = which == 0 ? b0 : (which == 1 ? b1 : b2);
      float bv = bias[cl];
      if (which == 2) {  // V^T: 4 consecutive seq rows pack into one 8B store
        ushort4 pk;
        pk.x = f2bf(acc[i][j][0] + bv);
        pk.y = f2bf(acc[i][j][1] + bv);
        pk.z = f2bf(acc[i][j][2] + bv);
        pk.w = f2bf(acc[i][j][3] + bv);
        *(ushort4*)(outVT + (long)cl * SEQ + row0) = pk;
      } else {  // Q/K head-major [h][s][80]
        int hh = cl / 80, d = cl - hh * 80;
        u16* o = (which == 0 ? outQ : outK) + ((long)hh * SEQ + row0) * 80 + d;
#pragma unroll
        for (int r = 0; r < 4; r++) o[r * 80] = f2bf(acc[i][j][r] + bv);
      }
    }
  }
}

// ------------- O-proj GEMM: 64x128 tile, BK=64, 8 waves (32x32 each) -------
__global__ __launch_bounds__(512) void gemm_oproj(
    const u16* __restrict__ A, const u16* __restrict__ B,
    const float* __restrict__ b0, float* __restrict__ outF) {
  __shared__ u16 As[2][64 * 64];
  __shared__ u16 Bs[2][128 * 64];
  const int N = DIM, K = DIM;
  const int tid = threadIdx.x;
  const int wave = tid >> 6, lane = tid & 63;
  const int lrow = lane & 15, lgrp = lane >> 4;
  const int wr = (wave >> 2) * 32, wc = (wave & 3) * 32;

  const int nwg = gridDim.x;  // 320
  const int lid = blockIdx.x;
  const int wg = (lid & 7) * (nwg >> 3) + (lid >> 3);
  const int bnC = N >> 7;
  const int bm = wg / bnC, bn = wg % bnC;

  const int rowA = tid >> 3;
  const int offA = ((tid & 7) ^ (rowA & 7)) * 8;
  int rowB[2], offB[2];
#pragma unroll
  for (int j = 0; j < 2; j++) {
    int cid = j * 512 + tid;
    rowB[j] = cid >> 3;
    offB[j] = ((cid & 7) ^ (rowB[j] & 7)) * 8;
  }
  const u16* Abase = A + (long)bm * 64 * K;
  const u16* Bbase = B + (long)bn * 128 * K;

  f32x4 acc[2][2] = {};
  const int NT = K >> 6;

#define OP_STAGE(buf, k0)                                                          \
  {                                                                                \
    GLOAD16(Abase + (long)rowA * K + (k0) + offA, &As[buf][(wave * 64) * 8]);      \
    _Pragma("unroll") for (int j = 0; j < 2; j++)                                  \
        GLOAD16(Bbase + (long)rowB[j] * K + (k0) + offB[j],                        \
                &Bs[buf][(j * 512 + wave * 64) * 8]);                              \
  }

  OP_STAGE(0, 0);

  for (int t = 0; t < NT; t++) {
    const int cur = t & 1;
    if (t + 1 < NT) {
      OP_STAGE(cur ^ 1, (t + 1) << 6);
      asm volatile("s_waitcnt vmcnt(3)" ::: "memory");
    } else {
      asm volatile("s_waitcnt vmcnt(0)" ::: "memory");
    }
    ACQ_BARRIER();
#pragma unroll
    for (int ks = 0; ks < 2; ks++) {
      const int rc = ((ks * 4 + lgrp) ^ (lrow & 7)) * 8;
      short8 af[2], bfr[2];
#pragma unroll
      for (int i = 0; i < 2; i++)
        af[i] = *(const short8*)&As[cur][(wr + i * 16 + lrow) * 64 + rc];
#pragma unroll
      for (int j = 0; j < 2; j++)
        bfr[j] = *(const short8*)&Bs[cur][(wc + j * 16 + lrow) * 64 + rc];
#pragma unroll
      for (int i = 0; i < 2; i++)
#pragma unroll
        for (int j = 0; j < 2; j++)
          acc[i][j] = __builtin_amdgcn_mfma_f32_16x16x32_bf16(af[i], bfr[j], acc[i][j], 0, 0, 0);
    }
    __builtin_amdgcn_s_barrier();
  }

#pragma unroll
  for (int i = 0; i < 2; i++) {
    int row0 = bm * 64 + wr + i * 16 + lgrp * 4;
#pragma unroll
    for (int j = 0; j < 2; j++) {
      int col = bn * 128 + wc + j * 16 + lrow;
      float bv = b0[col];
#pragma unroll
      for (int r = 0; r < 4; r++)
        outF[(long)(row0 + r) * DIM + col] = acc[i][j][r] + bv;
    }
  }
}

// ---------------- RoPE (in place, head-major Q,K) ----------------
__global__ void rope_kernel(u16* __restrict__ Q, u16* __restrict__ Kt,
                            const float* __restrict__ cosT,
                            const float* __restrict__ sinT) {
  int idx = blockIdx.x * 256 + threadIdx.x;
  if (idx >= NH * SEQ * 40) return;
  int j = idx % 40;
  int t = idx / 40;
  int s = t & (SEQ - 1);
  int h = t >> 11;
  long base = ((long)h * SEQ + s) * 80;
  float c0 = cosT[s * HD + j], s0 = sinT[s * HD + j];
  float c1 = cosT[s * HD + j + 40], s1 = sinT[s * HD + j + 40];
  float q0 = bf2f(Q[base + j]), q1 = bf2f(Q[base + j + 40]);
  Q[base + j] = f2bf(q0 * c0 - q1 * s0);
  Q[base + j + 40] = f2bf(q1 * c1 + q0 * s1);
  float k0 = bf2f(Kt[base + j]), k1 = bf2f(Kt[base + j + 40]);
  Kt[base + j] = f2bf(k0 * c0 - k1 * s0);
  Kt[base + j + 40] = f2bf(k1 * c1 + k0 * s1);
}

// ---------------- Flash attention v5: counted-vmcnt staged K/V^T -----------
// Q,K head-major [h][s][80]; VT [1280][SEQ] (per-head [80][SEQ]).
// Swapped QK^T (mfma(K,Q)) -> lane-local softmax over 16 keys.
// Uniform 5 gload_lds per thread per tile -> s_waitcnt vmcnt(5).
__global__ __launch_bounds__(256) void attn_kernel(
    const u16* __restrict__ Q, const u16* __restrict__ K,
    const u16* __restrict__ VT, u16* __restrict__ O, const int* __restrict__ cu) {
  const int h = blockIdx.x;
  const int g = blockIdx.y;
  const int qt = blockIdx.z;
  const int s0 = cu[g], s1 = cu[g + 1];
  const int qbase = s0 + qt * 64;
  if (qbase >= s1) return;

  __shared__ u16 k_s[2][64 * 80];   // [key][d], 16B chunks XOR-swizzled (c<8)
  __shared__ u16 vt_s[2][80 * 64];  // [d][key], 8 chunks/row XOR-swizzled
  __shared__ u16 ps[4 * 16 * 64];   // per-wave P [qrow][key], swizzled

  const int tid = threadIdx.x;
  const int wave = tid >> 6, lane = tid & 63;
  const int lrow = lane & 15, lgrp = lane >> 4;

  const u16* Kh = K + (long)h * SEQ * 80;
  const u16* Vh = VT + (long)h * 80 * SEQ;

  // Q fragments from global (one-time gather), head-major
  int qrow = qbase + wave * 16 + lrow;
  const u16* qptr = Q + ((long)h * SEQ + qrow) * 80;
  short8 aq[3];
#pragma unroll
  for (int ks = 0; ks < 3; ks++) {
    short8 z = {};
    if (ks < 2 || lgrp < 2) z = *(const short8*)(qptr + ks * 32 + lgrp * 8);
    aq[ks] = z;
  }

  f32x4 o_acc[5] = {};
  float m_r = -1e30f, l_r = 0.f;
  const float scale = 0.11180339887498949f;  // 1/sqrt(80)

  const int nk = (s1 - s0 + 63) / 64;  // 8

  // 1280 16B chunks per tile (K: 0..639, V^T: 640..1279), 5 per thread.
  // chunk<640 is wave-uniform per (j,wave) slab since 640 % 64 == 0.
#define STAGE_KV(buf, kb)                                                          \
  {                                                                                \
    _Pragma("unroll") for (int j = 0; j < 5; j++) {                                \
      int chunk = j * 256 + tid;                                                   \
      if (chunk < 640) {                                                           \
        int krow = chunk / 10, c = chunk - krow * 10;                              \
        int cs = c < 8 ? (c ^ (krow & 7)) : c;                                     \
        GLOAD16(Kh + ((long)((kb) + krow)) * 80 + cs * 8,                          \
                &k_s[buf][(j * 256 + wave * 64) * 8]);                             \
      } else {                                                                     \
        int vc = chunk - 640;                                                      \
        int d = vc >> 3, c = vc & 7;                                               \
        GLOAD16(Vh + (long)d * SEQ + (kb) + ((c ^ (d & 7)) * 8),                   \
                &vt_s[buf][(j * 256 + wave * 64 - 640) * 8]);                      \
      }                                                                            \
    }                                                                              \
  }

  STAGE_KV(0, s0);

  for (int ck = 0; ck < nk; ck++) {
    const int kb = s0 + ck * 64;
    const int cur = ck & 1;
    if (ck + 1 < nk) {
      STAGE_KV(cur ^ 1, kb + 64);
      asm volatile("s_waitcnt vmcnt(5)" ::: "memory");
    } else {
      asm volatile("s_waitcnt vmcnt(0)" ::: "memory");
    }
    ACQ_BARRIER();

    // S^T = K * Q^T : sa[n] = keys n*16..+15 (rows), q cols
    f32x4 sa[4] = {};
#pragma unroll
    for (int n = 0; n < 4; n++) {
      int row = n * 16 + lrow;
#pragma unroll
      for (int ks = 0; ks < 3; ks++) {
        short8 kf = {};
        if (ks < 2) {
          int cl = (ks * 4 + lgrp) ^ (row & 7);
          kf = *(const short8*)&k_s[cur][row * 80 + cl * 8];
        } else if (lgrp < 2) {
          kf = *(const short8*)&k_s[cur][row * 80 + (8 + lgrp) * 8];
        }
        sa[n] = __builtin_amdgcn_mfma_f32_16x16x32_bf16(kf, aq[ks], sa[n], 0, 0, 0);
      }
    }

    // lane-local softmax (16 keys per lane for q-row lrow)
    float pm = -1e30f;
    float pv[4][4];
#pragma unroll
    for (int n = 0; n < 4; n++)
#pragma unroll
      for (int r = 0; r < 4; r++) {
        float v = sa[n][r] * scale;
        pv[n][r] = v;
        pm = fmaxf(pm, v);
      }
    pm = fmaxf(pm, __shfl_xor(pm, 16));
    pm = fmaxf(pm, __shfl_xor(pm, 32));
    float mnew = fmaxf(m_r, pm);
    float sc = __expf(m_r - mnew);
    float ls = 0.f;
#pragma unroll
    for (int n = 0; n < 4; n++)
#pragma unroll
      for (int r = 0; r < 4; r++) {
        float e = __expf(pv[n][r] - mnew);
        pv[n][r] = e;
        ls += e;
      }
    ls += __shfl_xor(ls, 16);
    ls += __shfl_xor(ls, 32);
    l_r = l_r * sc + ls;
    m_r = mnew;

#pragma unroll
    for (int r = 0; r < 4; r++) {
      float scr = __shfl(sc, lgrp * 4 + r);
#pragma unroll
      for (int nf = 0; nf < 5; nf++) o_acc[nf][r] *= scr;
    }

    // P -> per-wave LDS (8B packed), swizzled; no barrier (per-wave, in-order)
#pragma unroll
    for (int n = 0; n < 4; n++) {
      uint2 w;
      w.x = (unsigned)f2bf(pv[n][0]) | ((unsigned)f2bf(pv[n][1]) << 16);
      w.y = (unsigned)f2bf(pv[n][2]) | ((unsigned)f2bf(pv[n][3]) << 16);
      int keybase = n * 16 + lgrp * 4;
      int cw = (keybase >> 3) ^ (lrow & 7);
      *(uint2*)&ps[wave * 1024 + lrow * 64 + cw * 8 + (keybase & 7)] = w;
    }

    // PV: o += P * V (A = P rows=q, B = V^T rows=d)
#pragma unroll
    for (int ks = 0; ks < 2; ks++) {
      int g8 = ks * 4 + lgrp;
      short8 pf = *(const short8*)&ps[wave * 1024 + lrow * 64 + (g8 ^ (lrow & 7)) * 8];
#pragma unroll
      for (int nf = 0; nf < 5; nf++) {
        int row = nf * 16 + lrow;
        short8 vf = *(const short8*)&vt_s[cur][row * 64 + (g8 ^ (row & 7)) * 8];
        o_acc[nf] = __builtin_amdgcn_mfma_f32_16x16x32_bf16(pf, vf, o_acc[nf], 0, 0, 0);
      }
    }
    __builtin_amdgcn_s_barrier();  // release: all reads of cur done
  }

  // epilogue: normalize, write row-major [s][1280] for O-proj
#pragma unroll
  for (int r = 0; r < 4; r++) {
    float lr = __shfl(l_r, lgrp * 4 + r);
    float inv = 1.0f / lr;
    int row = qbase + wave * 16 + lgrp * 4 + r;
#pragma unroll
    for (int nf = 0; nf < 5; nf++)
      O[(long)row * DIM + h * HD + nf * 16 + lrow] = f2bf(o_acc[nf][r] * inv);
  }
}

extern "C" void kernel_launch(void* const* d_in, const int* in_sizes, int n_in,
                              void* d_out, int out_size, void* d_ws, size_t ws_size,
                              hipStream_t stream) {
  const float* hs = (const float*)d_in[0];
  const float* Wq = (const float*)d_in[1];
  const float* bq = (const float*)d_in[2];
  const float* Wk = (const float*)d_in[3];
  const float* bk = (const float*)d_in[4];
  const float* Wv = (const float*)d_in[5];
  const float* bv = (const float*)d_in[6];
  const float* Wo = (const float*)d_in[7];
  const float* bo = (const float*)d_in[8];
  const float* cosT = (const float*)d_in[9];
  const float* sinT = (const float*)d_in[10];
  const int* cu = (const int*)d_in[11];
  const int nseg = in_sizes[11] - 1;  // 4

  char* ws = (char*)d_ws;
  u16* hs_b = (u16*)(ws);
  u16* wq_b = (u16*)(ws + 5242880);   // [Wq;Wk;Wv;Wo] contiguous bf16
  u16* wo_b = (u16*)(ws + 15073280);
  u16* q_b  = (u16*)(ws + 18350080);  // head-major [16][2048][80]
  u16* k_b  = (u16*)(ws + 23592960);  // head-major
  u16* vt_g = (u16*)(ws + 28835840);  // V^T [1280][2048]
  u16* ao_b = (u16*)(ws + 34078720);  // [2048][1280]

  const int nh = SEQ * DIM;
  const int nw = DIM * DIM;
  cvt5<<<dim3(nh / 1024, 5), 256, 0, stream>>>(hs, Wq, Wk, Wv, Wo, hs_b, wq_b, nh, nw);

  // merged QKV GEMM: grid = 16*30 = 480 blocks, 512 threads
  gemm_qkv128<<<(SEQ / 128) * (3 * DIM / 128), 512, 0, stream>>>(
      hs_b, wq_b, bq, bk, bv, q_b, k_b, vt_g);

  rope_kernel<<<(NH * SEQ * 40) / 256, 256, 0, stream>>>(q_b, k_b, cosT, sinT);

  dim3 ga(NH, nseg, (SEQ / nseg + 63) / 64);
  attn_kernel<<<ga, 256, 0, stream>>>(q_b, k_b, vt_g, ao_b, cu);

  // O-proj: grid = 32*10 = 320 blocks, 512 threads
  gemm_oproj<<<(SEQ / 64) * (DIM / 128), 512, 0, stream>>>(ao_b, wo_b, bo,
                                                           (float*)d_out);
}

// Round 8
// 81.626 us; speedup vs baseline: 1.8541x; 1.0320x over previous
//
#include <hip/hip_runtime.h>

#define SEQ 2048
#define DIM 1280
#define NH 16
#define HD 80

typedef __attribute__((ext_vector_type(8))) short short8;
typedef __attribute__((ext_vector_type(4))) float f32x4;
typedef unsigned short u16;

__device__ inline u16 f2bf(float f) {
  unsigned u = __builtin_bit_cast(unsigned, f);
  u += 0x7FFFu + ((u >> 16) & 1u);
  return (u16)(u >> 16);
}
__device__ inline float bf2f(u16 h) {
  unsigned u = ((unsigned)h) << 16;
  return __builtin_bit_cast(float, u);
}

// async global->LDS, 16B per lane, dest = wave-uniform base + lane*16
#define GLOAD16(gsrc, ldst)                                                          \
  __builtin_amdgcn_global_load_lds((const __attribute__((address_space(1))) unsigned*)(gsrc), \
                                   (__attribute__((address_space(3))) unsigned*)(ldst), 16, 0, 0)

#define ACQ_BARRIER()                    \
  __builtin_amdgcn_s_barrier();          \
  __builtin_amdgcn_sched_barrier(0)

// ---------------- all f32 -> bf16 conversions in one launch ----------------
__global__ void cvt5(const float* __restrict__ s0, const float* __restrict__ s1,
                     const float* __restrict__ s2, const float* __restrict__ s3,
                     const float* __restrict__ s4, u16* __restrict__ hs_b,
                     u16* __restrict__ w_b, int nh, int nw) {
  int y = blockIdx.y;
  const float* src = y == 0 ? s0 : (y == 1 ? s1 : (y == 2 ? s2 : (y == 3 ? s3 : s4)));
  int n = y == 0 ? nh : nw;
  u16* dst = y == 0 ? hs_b : w_b + (long)(y - 1) * nw;
  int i = (blockIdx.x * 256 + threadIdx.x) * 4;
  if (i >= n) return;
  float4 v = *(const float4*)(src + i);
  ushort4 pk;
  pk.x = f2bf(v.x); pk.y = f2bf(v.y); pk.z = f2bf(v.z); pk.w = f2bf(v.w);
  *(ushort4*)(dst + i) = pk;
}

// ------------- QKV GEMM: 128x128 tile, BK=64, 8 waves (64x32 each, 4x2) -----
// Counted-vmcnt double-buffer (T4): stage(t+1) -> s_waitcnt vmcnt(4) ->
// barrier -> compute(t) -> barrier. Loads never drained in main loop.
__global__ __launch_bounds__(512) void gemm_qkv128(
    const u16* __restrict__ A, const u16* __restrict__ B,
    const float* __restrict__ b0, const float* __restrict__ b1,
    const float* __restrict__ b2, u16* __restrict__ outQ, u16* __restrict__ outK,
    u16* __restrict__ outVT) {
  __shared__ u16 As[2][128 * 64];
  __shared__ u16 Bs[2][128 * 64];
  const int K = DIM;
  const int tid = threadIdx.x;
  const int wave = tid >> 6, lane = tid & 63;
  const int lrow = lane & 15, lgrp = lane >> 4;
  const int wr = (wave >> 2) * 64, wc = (wave & 3) * 32;

  const int nwg = gridDim.x;  // 480, %8==0
  const int lid = blockIdx.x;
  const int wg = (lid & 7) * (nwg >> 3) + (lid >> 3);
  const int bm = wg & 15, bn = wg >> 4;  // 16 M-blocks, 30 N-blocks

  int rowS[2], offS[2];
#pragma unroll
  for (int j = 0; j < 2; j++) {
    int cid = j * 512 + tid;
    rowS[j] = cid >> 3;
    offS[j] = ((cid & 7) ^ (rowS[j] & 7)) * 8;
  }
  const u16* Abase = A + (long)bm * 128 * K;
  const u16* Bbase = B + (long)bn * 128 * K;

  f32x4 acc[4][2] = {};
  const int NT = K >> 6;  // 20

#define QKV_STAGE(buf, k0)                                                         \
  {                                                                                \
    _Pragma("unroll") for (int j = 0; j < 2; j++)                                  \
        GLOAD16(Abase + (long)rowS[j] * K + (k0) + offS[j],                        \
                &As[buf][(j * 512 + wave * 64) * 8]);                              \
    _Pragma("unroll") for (int j = 0; j < 2; j++)                                  \
        GLOAD16(Bbase + (long)rowS[j] * K + (k0) + offS[j],                        \
                &Bs[buf][(j * 512 + wave * 64) * 8]);                              \
  }

  QKV_STAGE(0, 0);

  for (int t = 0; t < NT; t++) {
    const int cur = t & 1;
    if (t + 1 < NT) {
      QKV_STAGE(cur ^ 1, (t + 1) << 6);
      asm volatile("s_waitcnt vmcnt(4)" ::: "memory");
    } else {
      asm volatile("s_waitcnt vmcnt(0)" ::: "memory");
    }
    ACQ_BARRIER();
#pragma unroll
    for (int ks = 0; ks < 2; ks++) {
      const int rc = ((ks * 4 + lgrp) ^ (lrow & 7)) * 8;
      short8 af[4], bfr[2];
#pragma unroll
      for (int i = 0; i < 4; i++)
        af[i] = *(const short8*)&As[cur][(wr + i * 16 + lrow) * 64 + rc];
#pragma unroll
      for (int j = 0; j < 2; j++)
        bfr[j] = *(const short8*)&Bs[cur][(wc + j * 16 + lrow) * 64 + rc];
#pragma unroll
      for (int i = 0; i < 4; i++)
#pragma unroll
        for (int j = 0; j < 2; j++)
          acc[i][j] = __builtin_amdgcn_mfma_f32_16x16x32_bf16(af[i], bfr[j], acc[i][j], 0, 0, 0);
    }
    __builtin_amdgcn_s_barrier();  // release: all reads of cur done
  }

#pragma unroll
  for (int i = 0; i < 4; i++) {
    int row0 = bm * 128 + wr + i * 16 + lgrp * 4;
#pragma unroll
    for (int j = 0; j < 2; j++) {
      int col = bn * 128 + wc + j * 16 + lrow;
      int which = col / 1280;  // uniform per block (bn-decided)
      int cl = col - which * 1280;
      const float* bias = which == 0 ? b0 : (which == 1 ? b1 : b2);
      float bv = bias[cl];
      if (which == 2) {  // V^T: 4 consecutive seq rows pack into one 8B store
        ushort4 pk;
        pk.x = f2bf(acc[i][j][0] + bv);
        pk.y = f2bf(acc[i][j][1] + bv);
        pk.z = f2bf(acc[i][j][2] + bv);
        pk.w = f2bf(acc[i][j][3] + bv);
        *(ushort4*)(outVT + (long)cl * SEQ + row0) = pk;
      } else {  // Q/K head-major [h][s][80]
        int hh = cl / 80, d = cl - hh * 80;
        u16* o = (which == 0 ? outQ : outK) + ((long)hh * SEQ + row0) * 80 + d;
#pragma unroll
        for (int r = 0; r < 4; r++) o[r * 80] = f2bf(acc[i][j][r] + bv);
      }
    }
  }
}

// ------------- O-proj GEMM: 64x128 tile, BK=64, 8 waves (32x32 each) -------
__global__ __launch_bounds__(512) void gemm_oproj(
    const u16* __restrict__ A, const u16* __restrict__ B,
    const float* __restrict__ b0, float* __restrict__ outF) {
  __shared__ u16 As[2][64 * 64];
  __shared__ u16 Bs[2][128 * 64];
  const int N = DIM, K = DIM;
  const int tid = threadIdx.x;
  const int wave = tid >> 6, lane = tid & 63;
  const int lrow = lane & 15, lgrp = lane >> 4;
  const int wr = (wave >> 2) * 32, wc = (wave & 3) * 32;

  const int nwg = gridDim.x;  // 320
  const int lid = blockIdx.x;
  const int wg = (lid & 7) * (nwg >> 3) + (lid >> 3);
  const int bnC = N >> 7;
  const int bm = wg / bnC, bn = wg % bnC;

  const int rowA = tid >> 3;
  const int offA = ((tid & 7) ^ (rowA & 7)) * 8;
  int rowB[2], offB[2];
#pragma unroll
  for (int j = 0; j < 2; j++) {
    int cid = j * 512 + tid;
    rowB[j] = cid >> 3;
    offB[j] = ((cid & 7) ^ (rowB[j] & 7)) * 8;
  }
  const u16* Abase = A + (long)bm * 64 * K;
  const u16* Bbase = B + (long)bn * 128 * K;

  f32x4 acc[2][2] = {};
  const int NT = K >> 6;

#define OP_STAGE(buf, k0)                                                          \
  {                                                                                \
    GLOAD16(Abase + (long)rowA * K + (k0) + offA, &As[buf][(wave * 64) * 8]);      \
    _Pragma("unroll") for (int j = 0; j < 2; j++)                                  \
        GLOAD16(Bbase + (long)rowB[j] * K + (k0) + offB[j],                        \
                &Bs[buf][(j * 512 + wave * 64) * 8]);                              \
  }

  OP_STAGE(0, 0);

  for (int t = 0; t < NT; t++) {
    const int cur = t & 1;
    if (t + 1 < NT) {
      OP_STAGE(cur ^ 1, (t + 1) << 6);
      asm volatile("s_waitcnt vmcnt(3)" ::: "memory");
    } else {
      asm volatile("s_waitcnt vmcnt(0)" ::: "memory");
    }
    ACQ_BARRIER();
#pragma unroll
    for (int ks = 0; ks < 2; ks++) {
      const int rc = ((ks * 4 + lgrp) ^ (lrow & 7)) * 8;
      short8 af[2], bfr[2];
#pragma unroll
      for (int i = 0; i < 2; i++)
        af[i] = *(const short8*)&As[cur][(wr + i * 16 + lrow) * 64 + rc];
#pragma unroll
      for (int j = 0; j < 2; j++)
        bfr[j] = *(const short8*)&Bs[cur][(wc + j * 16 + lrow) * 64 + rc];
#pragma unroll
      for (int i = 0; i < 2; i++)
#pragma unroll
        for (int j = 0; j < 2; j++)
          acc[i][j] = __builtin_amdgcn_mfma_f32_16x16x32_bf16(af[i], bfr[j], acc[i][j], 0, 0, 0);
    }
    __builtin_amdgcn_s_barrier();
  }

#pragma unroll
  for (int i = 0; i < 2; i++) {
    int row0 = bm * 64 + wr + i * 16 + lgrp * 4;
#pragma unroll
    for (int j = 0; j < 2; j++) {
      int col = bn * 128 + wc + j * 16 + lrow;
      float bv = b0[col];
#pragma unroll
      for (int r = 0; r < 4; r++)
        outF[(long)(row0 + r) * DIM + col] = acc[i][j][r] + bv;
    }
  }
}

// ---------------- RoPE (in place, head-major Q,K) ----------------
__global__ void rope_kernel(u16* __restrict__ Q, u16* __restrict__ Kt,
                            const float* __restrict__ cosT,
                            const float* __restrict__ sinT) {
  int idx = blockIdx.x * 256 + threadIdx.x;
  if (idx >= NH * SEQ * 40) return;
  int j = idx % 40;
  int t = idx / 40;
  int s = t & (SEQ - 1);
  int h = t >> 11;
  long base = ((long)h * SEQ + s) * 80;
  float c0 = cosT[s * HD + j], s0 = sinT[s * HD + j];
  float c1 = cosT[s * HD + j + 40], s1 = sinT[s * HD + j + 40];
  float q0 = bf2f(Q[base + j]), q1 = bf2f(Q[base + j + 40]);
  Q[base + j] = f2bf(q0 * c0 - q1 * s0);
  Q[base + j + 40] = f2bf(q1 * c1 + q0 * s1);
  float k0 = bf2f(Kt[base + j]), k1 = bf2f(Kt[base + j + 40]);
  Kt[base + j] = f2bf(k0 * c0 - k1 * s0);
  Kt[base + j + 40] = f2bf(k1 * c1 + k0 * s1);
}

// ------------- Flash attention v6: QBLK=128, KVBLK=128, 8 waves ------------
// Q,K head-major [h][s][80]; VT [1280][SEQ] (per-head [80][SEQ]).
// Swapped QK^T (mfma(K,Q)) -> lane-local softmax over 32 keys.
// 40 gload_lds per tile = exactly 5 per wave -> counted vmcnt(5).
// XCD-grouped flat grid: 4 q-tiles of a (head,seg) share one XCD's L2.
__global__ __launch_bounds__(512) void attn_kernel(
    const u16* __restrict__ Q, const u16* __restrict__ K,
    const u16* __restrict__ VT, u16* __restrict__ O, const int* __restrict__ cu) {
  // decode XCD-grouped flat id: u = (b&7)*32 + (b>>3); u = hg*4 + qt
  const int b = blockIdx.x;
  const int u = ((b & 7) << 5) + (b >> 3);
  const int qt = u & 3;
  const int hg = u >> 2;       // 0..63
  const int h = hg >> 2;       // 16 heads
  const int g = hg & 3;        // 4 segments
  const int s0 = cu[g], s1 = cu[g + 1];
  const int qbase = s0 + qt * 128;
  if (qbase >= s1) return;

  __shared__ u16 k_s[2][128 * 80];   // [key][d], 10 chunks/row, XOR-swz (c<8)
  __shared__ u16 vt_s[2][80 * 128];  // [d][key], 16 chunks/row, XOR-swz
  __shared__ u16 ps[8 * 16 * 128];   // per-wave P [qrow][key], swizzled

  const int tid = threadIdx.x;
  const int wave = tid >> 6, lane = tid & 63;
  const int lrow = lane & 15, lgrp = lane >> 4;

  const u16* Kh = K + (long)h * SEQ * 80;
  const u16* Vh = VT + (long)h * 80 * SEQ;

  // Q fragments from global (one-time), head-major
  int qrow = qbase + wave * 16 + lrow;
  const u16* qptr = Q + ((long)h * SEQ + qrow) * 80;
  short8 aq[3];
#pragma unroll
  for (int ks = 0; ks < 3; ks++) {
    short8 z = {};
    if (ks < 2 || lgrp < 2) z = *(const short8*)(qptr + ks * 32 + lgrp * 8);
    aq[ks] = z;
  }

  f32x4 o_acc[5] = {};
  float m_r = -1e30f, l_r = 0.f;
  const float scale = 0.11180339887498949f;  // 1/sqrt(80)

  const int nk = (s1 - s0 + 127) / 128;  // 4

  // 2560 16B chunks per tile: K = [0,1280), V^T = [1280,2560).
  // chunk = j*512 + tid; (j,wave) slabs stay in one region (1280 % 64 == 0).
#define STAGE_KV(buf, kb)                                                          \
  {                                                                                \
    _Pragma("unroll") for (int j = 0; j < 5; j++) {                                \
      int chunk = j * 512 + tid;                                                   \
      if (chunk < 1280) {                                                          \
        int krow = chunk / 10, c = chunk - krow * 10;                              \
        int cs = c < 8 ? (c ^ (krow & 7)) : c;                                     \
        GLOAD16(Kh + ((long)((kb) + krow)) * 80 + cs * 8,                          \
                &k_s[buf][(j * 512 + wave * 64) * 8]);                             \
      } else {                                                                     \
        int vc = chunk - 1280;                                                     \
        int d = vc >> 4, c = vc & 15;                                              \
        GLOAD16(Vh + (long)d * SEQ + (kb) + ((c ^ (d & 7)) * 8),                   \
                &vt_s[buf][(j * 512 + wave * 64 - 1280) * 8]);                     \
      }                                                                            \
    }                                                                              \
  }

  STAGE_KV(0, s0);

  for (int ck = 0; ck < nk; ck++) {
    const int kb = s0 + ck * 128;
    const int cur = ck & 1;
    if (ck + 1 < nk) {
      STAGE_KV(cur ^ 1, kb + 128);
      asm volatile("s_waitcnt vmcnt(5)" ::: "memory");
    } else {
      asm volatile("s_waitcnt vmcnt(0)" ::: "memory");
    }
    ACQ_BARRIER();

    // S^T = K * Q^T : sa[n] = keys n*16..+15 (rows), q cols
    f32x4 sa[8];
#pragma unroll
    for (int n = 0; n < 8; n++) sa[n] = (f32x4){0.f, 0.f, 0.f, 0.f};
#pragma unroll
    for (int n = 0; n < 8; n++) {
      int row = n * 16 + lrow;
#pragma unroll
      for (int ks = 0; ks < 3; ks++) {
        short8 kf = {};
        if (ks < 2) {
          int cl = (ks * 4 + lgrp) ^ (row & 7);
          kf = *(const short8*)&k_s[cur][row * 80 + cl * 8];
        } else if (lgrp < 2) {
          kf = *(const short8*)&k_s[cur][row * 80 + (8 + lgrp) * 8];
        }
        sa[n] = __builtin_amdgcn_mfma_f32_16x16x32_bf16(kf, aq[ks], sa[n], 0, 0, 0);
      }
    }

    // lane-local softmax (32 keys per lane for q-row lrow)
    float pm = -1e30f;
    float pv[8][4];
#pragma unroll
    for (int n = 0; n < 8; n++)
#pragma unroll
      for (int r = 0; r < 4; r++) {
        float v = sa[n][r] * scale;
        pv[n][r] = v;
        pm = fmaxf(pm, v);
      }
    pm = fmaxf(pm, __shfl_xor(pm, 16));
    pm = fmaxf(pm, __shfl_xor(pm, 32));
    float mnew = fmaxf(m_r, pm);
    float sc = __expf(m_r - mnew);
    float ls = 0.f;
#pragma unroll
    for (int n = 0; n < 8; n++)
#pragma unroll
      for (int r = 0; r < 4; r++) {
        float e = __expf(pv[n][r] - mnew);
        pv[n][r] = e;
        ls += e;
      }
    ls += __shfl_xor(ls, 16);
    ls += __shfl_xor(ls, 32);
    l_r = l_r * sc + ls;
    m_r = mnew;

#pragma unroll
    for (int r = 0; r < 4; r++) {
      float scr = __shfl(sc, lgrp * 4 + r);
#pragma unroll
      for (int nf = 0; nf < 5; nf++) o_acc[nf][r] *= scr;
    }

    // P -> per-wave LDS (8B packed), swizzled; no barrier (per-wave, in-order)
#pragma unroll
    for (int n = 0; n < 8; n++) {
      uint2 w;
      w.x = (unsigned)f2bf(pv[n][0]) | ((unsigned)f2bf(pv[n][1]) << 16);
      w.y = (unsigned)f2bf(pv[n][2]) | ((unsigned)f2bf(pv[n][3]) << 16);
      int keybase = n * 16 + lgrp * 4;
      int cw = (keybase >> 3) ^ (lrow & 7);
      *(uint2*)&ps[wave * 2048 + lrow * 128 + cw * 8 + (keybase & 7)] = w;
    }

    // PV: o += P * V (A = P rows=q, B = V^T rows=d)
#pragma unroll
    for (int ks = 0; ks < 4; ks++) {
      int g8 = ks * 4 + lgrp;
      short8 pf = *(const short8*)&ps[wave * 2048 + lrow * 128 + (g8 ^ (lrow & 7)) * 8];
#pragma unroll
      for (int nf = 0; nf < 5; nf++) {
        int d = nf * 16 + lrow;
        short8 vf = *(const short8*)&vt_s[cur][d * 128 + (g8 ^ (d & 7)) * 8];
        o_acc[nf] = __builtin_amdgcn_mfma_f32_16x16x32_bf16(pf, vf, o_acc[nf], 0, 0, 0);
      }
    }
    __builtin_amdgcn_s_barrier();  // release: all reads of cur done
  }

  // epilogue: normalize, write row-major [s][1280] for O-proj
#pragma unroll
  for (int r = 0; r < 4; r++) {
    float lr = __shfl(l_r, lgrp * 4 + r);
    float inv = 1.0f / lr;
    int row = qbase + wave * 16 + lgrp * 4 + r;
#pragma unroll
    for (int nf = 0; nf < 5; nf++)
      O[(long)row * DIM + h * HD + nf * 16 + lrow] = f2bf(o_acc[nf][r] * inv);
  }
}

extern "C" void kernel_launch(void* const* d_in, const int* in_sizes, int n_in,
                              void* d_out, int out_size, void* d_ws, size_t ws_size,
                              hipStream_t stream) {
  const float* hs = (const float*)d_in[0];
  const float* Wq = (const float*)d_in[1];
  const float* bq = (const float*)d_in[2];
  const float* Wk = (const float*)d_in[3];
  const float* bk = (const float*)d_in[4];
  const float* Wv = (const float*)d_in[5];
  const float* bv = (const float*)d_in[6];
  const float* Wo = (const float*)d_in[7];
  const float* bo = (const float*)d_in[8];
  const float* cosT = (const float*)d_in[9];
  const float* sinT = (const float*)d_in[10];
  const int* cu = (const int*)d_in[11];

  char* ws = (char*)d_ws;
  u16* hs_b = (u16*)(ws);
  u16* wq_b = (u16*)(ws + 5242880);   // [Wq;Wk;Wv;Wo] contiguous bf16
  u16* wo_b = (u16*)(ws + 15073280);
  u16* q_b  = (u16*)(ws + 18350080);  // head-major [16][2048][80]
  u16* k_b  = (u16*)(ws + 23592960);  // head-major
  u16* vt_g = (u16*)(ws + 28835840);  // V^T [1280][2048]
  u16* ao_b = (u16*)(ws + 34078720);  // [2048][1280]

  const int nh = SEQ * DIM;
  const int nw = DIM * DIM;
  cvt5<<<dim3(nh / 1024, 5), 256, 0, stream>>>(hs, Wq, Wk, Wv, Wo, hs_b, wq_b, nh, nw);

  // merged QKV GEMM: grid = 16*30 = 480 blocks, 512 threads
  gemm_qkv128<<<(SEQ / 128) * (3 * DIM / 128), 512, 0, stream>>>(
      hs_b, wq_b, bq, bk, bv, q_b, k_b, vt_g);

  rope_kernel<<<(NH * SEQ * 40) / 256, 256, 0, stream>>>(q_b, k_b, cosT, sinT);

  // attention: 256 blocks (1/CU), 512 threads, XCD-grouped flat grid
  attn_kernel<<<NH * 4 * (SEQ / 4 / 128), 512, 0, stream>>>(q_b, k_b, vt_g, ao_b, cu);

  // O-proj: grid = 32*10 = 320 blocks, 512 threads
  gemm_oproj<<<(SEQ / 64) * (DIM / 128), 512, 0, stream>>>(ao_b, wo_b, bo,
                                                           (float*)d_out);
}